// Round 11
// baseline (310.157 us; speedup 1.0000x reference)
//
#include <hip/hip_runtime.h>
#include <hip/hip_bf16.h>
#include <float.h>
#include <math.h>

#define NN   50000
#define BB   50
#define NPGc 1000
#define EE   300000
#define HH   256
#define FIN  79
#define KK   500
#define GR   32      // gemm rows per block

typedef __hip_bfloat16 bf16;
typedef float v2f __attribute__((ext_vector_type(2)));

__device__ __forceinline__ float bfbits(unsigned short h) {
    return __uint_as_float(((unsigned int)h) << 16);
}
__device__ __forceinline__ float ldf(const void* p, int i, bool f32) {
    return f32 ? ((const float*)p)[i] : bfbits(((const unsigned short*)p)[i]);
}
__device__ __forceinline__ float4 ldf4(const void* p, int i, bool f32) {
    if (f32) return ((const float4*)p)[i >> 2];
    ushort4 u = ((const ushort4*)p)[i >> 2];
    return make_float4(bfbits(u.x), bfbits(u.y), bfbits(u.z), bfbits(u.w));
}

// ---------------- count (+ dtype detect in the extra block) ----------------
// detect: first 10112 uint32 of W1 (40448 B, safe in both layouts). bf16-packed:
// low half is |w|<1 -> exp<128. fp32: low 16 bits are mantissa noise -> exp>=128
// about half the time.

__global__ void k_count(const int* __restrict__ edst, int* __restrict__ deg,
                        const unsigned int* __restrict__ w1, int* __restrict__ flag) {
    int t = threadIdx.x;
    if (blockIdx.x == gridDim.x - 1) {
        __shared__ int sm[256];
        int c = 0;
        for (int i = t; i < 10112; i += 256) {
            unsigned int e = (w1[i] >> 7) & 0xFFu;
            c += (e >= 128u) ? 1 : 0;
        }
        sm[t] = c;
        __syncthreads();
        for (int off = 128; off > 0; off >>= 1) {
            if (t < off) sm[t] += sm[t + off];
            __syncthreads();
        }
        if (t == 0) flag[0] = (sm[0] > 500) ? 1 : 0;
        return;
    }
    int e = blockIdx.x * 256 + t;
    if (e < EE) atomicAdd(&deg[edst[e]], 1);
}

// ---------------- CSR scan ----------------

__global__ void k_scan_block(const int* __restrict__ deg, int* __restrict__ partial,
                             int* __restrict__ bsums) {
    __shared__ int sm[256];
    int t = threadIdx.x;
    int i = blockIdx.x * 256 + t;
    int v = (i < NN) ? deg[i] : 0;
    sm[t] = v;
    __syncthreads();
    for (int off = 1; off < 256; off <<= 1) {
        int u = (t >= off) ? sm[t - off] : 0;
        __syncthreads();
        sm[t] += u;
        __syncthreads();
    }
    if (i < NN) partial[i] = sm[t];
    if (t == 255) bsums[blockIdx.x] = sm[255];
}

// finalize, with inline reduction of bsums[0..b) (grid=196 <= 256 threads)
__global__ void k_finalize(const int* __restrict__ deg, const int* __restrict__ partial,
                           const int* __restrict__ bsums, int* __restrict__ offsets,
                           float* __restrict__ dinv) {
    __shared__ int sm[256];
    int b = blockIdx.x;
    int t = threadIdx.x;
    sm[t] = (t < b) ? bsums[t] : 0;
    __syncthreads();
    for (int off = 128; off > 0; off >>= 1) {
        if (t < off) sm[t] += sm[t + off];
        __syncthreads();
    }
    int base = sm[0];
    int i = b * 256 + t;
    if (i >= NN) return;
    int incl = partial[i] + base;
    offsets[i] = incl - deg[i];
    if (i == NN - 1) offsets[NN] = incl;
    dinv[i] = rsqrtf((float)(deg[i] + 1));   // +1 self-loop
}

__global__ void k_fill(const int* __restrict__ esrc, const int* __restrict__ edst,
                       const int* __restrict__ offsets, int* __restrict__ cursor,
                       int* __restrict__ eidx) {
    int e = blockIdx.x * blockDim.x + threadIdx.x;
    if (e < EE) {
        int d = edst[e];
        int pos = atomicAdd(&cursor[d], 1);
        eidx[offsets[d] + pos] = esrc[e];
    }
}

// ---------------- layer 1: h1 = relu(GCN(one_hot(x), W1, b1)) ----------------
// Wave-per-node; lane-parallel prefetch of eidx/x/dinv, shfl-broadcast per edge
// so the row gathers issue back-to-back (no serial eidx->row chains).

__global__ __launch_bounds__(256) void k_layer1(
        const int* __restrict__ x, const int* __restrict__ offsets,
        const int* __restrict__ eidx, const float* __restrict__ dinv,
        const void* __restrict__ W1, const void* __restrict__ b1,
        const int* __restrict__ flag, float* __restrict__ h1) {
    bool f32 = (*flag != 0);
    int node = blockIdx.x * 4 + (threadIdx.x >> 6);
    int lane = threadIdx.x & 63;
    int ch = lane * 4;
    if (node >= NN) return;
    int beg = offsets[node], end = offsets[node + 1];
    float4 acc = make_float4(0.f, 0.f, 0.f, 0.f);
    for (int base = beg; base < end; base += 64) {
        int cnt = min(64, end - base);
        int p  = base + ((lane < cnt) ? lane : 0);
        int sl = eidx[p];
        int xl = x[sl];
        float dvl = dinv[sl];
        for (int q = 0; q < cnt; ++q) {
            int xs   = __shfl(xl, q, 64);
            float dv = __shfl(dvl, q, 64);
            float4 w = ldf4(W1, xs * HH + ch, f32);
            acc.x += dv * w.x; acc.y += dv * w.y; acc.z += dv * w.z; acc.w += dv * w.w;
        }
    }
    float di = dinv[node];
    float d2 = di * di;
    float4 ws = ldf4(W1, x[node] * HH + ch, f32);
    float4 bb = ldf4(b1, ch, f32);
    float4 o;
    o.x = fmaxf(di * acc.x + d2 * ws.x + bb.x, 0.f);
    o.y = fmaxf(di * acc.y + d2 * ws.y + bb.y, 0.f);
    o.z = fmaxf(di * acc.z + d2 * ws.z + bb.z, 0.f);
    o.w = fmaxf(di * acc.w + d2 * ws.w + bb.w, 0.f);
    ((float4*)h1)[(node * HH + ch) >> 2] = o;
}

// ---------------- fused agg2 + gemm2: h2 = relu((A_norm @ h1) @ W2 + b2) ----------
// Each block owns 32 rows. STAGE: each wave gathers its own 8 agg2 rows directly
// into the LDS A-tile (shfl-broadcast edge loop, identical fp32 op order to the
// old k_agg2 -> bit-identical results). The A-tile is wave-private (wave w writes
// and reads only rows w*8..w*8+7). COMPUTE: r10 loop — W2 streamed from global
// with one-group prefetch, float2 ext-vector accumulate (v_pk_fma_f32).
// XCD swizzle: 1563 = 8*195 + 3; b<1560 -> (b&7)*195+(b>>3), tail identity.
// Epilogue: h2 store + fused trel/troot scorer dots.

__global__ __launch_bounds__(256) void k_gemm2(
        const int* __restrict__ offsets, const int* __restrict__ eidx,
        const float* __restrict__ dinv, const float* __restrict__ h1,
        const void* __restrict__ W2, const void* __restrict__ b2,
        const void* __restrict__ Wrel, const void* __restrict__ Wroot,
        const int* __restrict__ flag,
        float* __restrict__ Y, float* __restrict__ trel, float* __restrict__ troot) {
    __shared__ float As[GR][HH];     // 32 KB, no pad (broadcast reads)
    bool f32 = (*flag != 0);
    int t = threadIdx.x;
    int c4 = t & 63;          // float4 column index: cols 4*c4 .. 4*c4+3
    int rg = t >> 6;          // wave id -> rows rg*8 .. rg*8+7
    int b = blockIdx.x;
    int grp = (b < 1560) ? ((b & 7) * 195 + (b >> 3)) : b;
    int r0 = grp * GR;
    int lane = t & 63;
    int ch = lane * 4;

    // ---- stage: gather this wave's 8 agg2 rows into As ----
    for (int rr = 0; rr < 8; ++rr) {
        int row = r0 + rg * 8 + rr;
        float4 acc = make_float4(0.f, 0.f, 0.f, 0.f);
        if (row < NN) {
            int beg = offsets[row], end = offsets[row + 1];
            for (int base = beg; base < end; base += 64) {
                int cnt = min(64, end - base);
                int p  = base + ((lane < cnt) ? lane : 0);
                int sl = eidx[p];
                float dvl = dinv[sl];
                for (int q = 0; q < cnt; ++q) {
                    int s    = __shfl(sl, q, 64);
                    float dv = __shfl(dvl, q, 64);
                    float4 v = ((const float4*)h1)[(s * HH + ch) >> 2];
                    acc.x += dv * v.x; acc.y += dv * v.y;
                    acc.z += dv * v.z; acc.w += dv * v.w;
                }
            }
            float di = dinv[row];
            float d2 = di * di;
            float4 v = ((const float4*)h1)[(row * HH + ch) >> 2];
            acc.x = di * acc.x + d2 * v.x;
            acc.y = di * acc.y + d2 * v.y;
            acc.z = di * acc.z + d2 * v.z;
            acc.w = di * acc.w + d2 * v.w;
        }
        *(float4*)&As[rg * 8 + rr][ch] = acc;
    }
    __syncthreads();   // safety only: tile is wave-private

    // ---- compute ----
    v2f accL[8], accH[8];
#pragma unroll
    for (int rr = 0; rr < 8; ++rr) { accL[rr] = (v2f)0.f; accH[rr] = (v2f)0.f; }

    if (f32) {
        const float* W = (const float*)W2;
        float4 w0 = *(const float4*)&W[0 * HH + c4 * 4];
        float4 w1 = *(const float4*)&W[1 * HH + c4 * 4];
        float4 w2 = *(const float4*)&W[2 * HH + c4 * 4];
        float4 w3 = *(const float4*)&W[3 * HH + c4 * 4];
        for (int k = 0; k < 256; k += 4) {
            float4 n0, n1, n2, n3;
            int kn = (k + 4) & 255;          // wraps to 0 on last iter (harmless)
            n0 = *(const float4*)&W[(kn + 0) * HH + c4 * 4];
            n1 = *(const float4*)&W[(kn + 1) * HH + c4 * 4];
            n2 = *(const float4*)&W[(kn + 2) * HH + c4 * 4];
            n3 = *(const float4*)&W[(kn + 3) * HH + c4 * 4];
            v2f w0L = {w0.x, w0.y}, w0H = {w0.z, w0.w};
            v2f w1L = {w1.x, w1.y}, w1H = {w1.z, w1.w};
            v2f w2L = {w2.x, w2.y}, w2H = {w2.z, w2.w};
            v2f w3L = {w3.x, w3.y}, w3H = {w3.z, w3.w};
#pragma unroll
            for (int rr = 0; rr < 8; ++rr) {
                float4 a = *(const float4*)&As[rg * 8 + rr][k];
                v2f ax = a.x, ay = a.y, az = a.z, aw = a.w;
                accL[rr] += ax * w0L; accH[rr] += ax * w0H;
                accL[rr] += ay * w1L; accH[rr] += ay * w1H;
                accL[rr] += az * w2L; accH[rr] += az * w2H;
                accL[rr] += aw * w3L; accH[rr] += aw * w3H;
            }
            w0 = n0; w1 = n1; w2 = n2; w3 = n3;
        }
    } else {
        const unsigned short* W = (const unsigned short*)W2;
        ushort4 u0 = *(const ushort4*)&W[0 * HH + c4 * 4];
        ushort4 u1 = *(const ushort4*)&W[1 * HH + c4 * 4];
        ushort4 u2 = *(const ushort4*)&W[2 * HH + c4 * 4];
        ushort4 u3 = *(const ushort4*)&W[3 * HH + c4 * 4];
        for (int k = 0; k < 256; k += 4) {
            ushort4 m0, m1, m2, m3;
            int kn = (k + 4) & 255;
            m0 = *(const ushort4*)&W[(kn + 0) * HH + c4 * 4];
            m1 = *(const ushort4*)&W[(kn + 1) * HH + c4 * 4];
            m2 = *(const ushort4*)&W[(kn + 2) * HH + c4 * 4];
            m3 = *(const ushort4*)&W[(kn + 3) * HH + c4 * 4];
            v2f w0L = {bfbits(u0.x), bfbits(u0.y)}, w0H = {bfbits(u0.z), bfbits(u0.w)};
            v2f w1L = {bfbits(u1.x), bfbits(u1.y)}, w1H = {bfbits(u1.z), bfbits(u1.w)};
            v2f w2L = {bfbits(u2.x), bfbits(u2.y)}, w2H = {bfbits(u2.z), bfbits(u2.w)};
            v2f w3L = {bfbits(u3.x), bfbits(u3.y)}, w3H = {bfbits(u3.z), bfbits(u3.w)};
#pragma unroll
            for (int rr = 0; rr < 8; ++rr) {
                float4 a = *(const float4*)&As[rg * 8 + rr][k];
                v2f ax = a.x, ay = a.y, az = a.z, aw = a.w;
                accL[rr] += ax * w0L; accH[rr] += ax * w0H;
                accL[rr] += ay * w1L; accH[rr] += ay * w1H;
                accL[rr] += az * w2L; accH[rr] += az * w2H;
                accL[rr] += aw * w3L; accH[rr] += aw * w3H;
            }
            u0 = m0; u1 = m1; u2 = m2; u3 = m3;
        }
    }

    float4 bb = ldf4(b2, c4 * 4, f32);
    float4 wr = ldf4(Wrel, c4 * 4, f32);
    float4 wo = ldf4(Wroot, c4 * 4, f32);
#pragma unroll
    for (int rr = 0; rr < 8; ++rr) {
        int row = r0 + rg * 8 + rr;
        float4 y;
        y.x = fmaxf(accL[rr].x + bb.x, 0.f);
        y.y = fmaxf(accL[rr].y + bb.y, 0.f);
        y.z = fmaxf(accH[rr].x + bb.z, 0.f);
        y.w = fmaxf(accH[rr].y + bb.w, 0.f);
        if (row < NN)
            *(float4*)&Y[row * HH + c4 * 4] = y;
        float sr = y.x * wr.x + y.y * wr.y + y.z * wr.z + y.w * wr.w;
        float so = y.x * wo.x + y.y * wo.y + y.z * wo.z + y.w * wo.w;
#pragma unroll
        for (int off = 32; off > 0; off >>= 1) {
            sr += __shfl_xor(sr, off, 64);
            so += __shfl_xor(so, off, 64);
        }
        if (c4 == 0 && row < NN) { trel[row] = sr; troot[row] = so; }
    }
}

// ---------------- fused: score -> per-graph top-k -> tanh-weighted max-pool ------
// One block per graph, 1024 threads (one bitonic element per thread).
// Desc score, asc index = jax.lax.top_k tie-break.

__global__ __launch_bounds__(1024) void k_topk(
        const int* __restrict__ offsets, const int* __restrict__ eidx,
        const float* __restrict__ trel, const float* __restrict__ troot,
        const void* __restrict__ brel, const int* __restrict__ flag,
        const float* __restrict__ h2, void* __restrict__ out) {
    __shared__ float s[1024];
    __shared__ int   id[1024];
    __shared__ float sw[KK];
    __shared__ int   snode[KK];
    bool f32 = (*flag != 0);
    int b = blockIdx.x, t = threadIdx.x;
    float br = ldf(brel, 0, f32);
    if (t < NPGc) {
        int node = b * NPGc + t;
        float sc = br + troot[node];
        int beg = offsets[node], end = offsets[node + 1];
        for (int p = beg; p < end; ++p) sc += trel[eidx[p]];
        s[t] = sc; id[t] = t;
    } else { s[t] = -FLT_MAX; id[t] = 0x7FFFFFFF; }
    for (int k = 2; k <= 1024; k <<= 1) {
        for (int j = k >> 1; j > 0; j >>= 1) {
            __syncthreads();
            int l = t ^ j;
            if (l > t) {
                float si = s[t], sl = s[l];
                int   ii = id[t], il = id[l];
                bool iFirst = (si > sl) || (si == sl && ii < il);
                bool doSwap = ((t & k) == 0) ? (!iFirst) : iFirst;
                if (doSwap) { s[t] = sl; s[l] = si; id[t] = il; id[l] = ii; }
            }
        }
    }
    __syncthreads();
    if (t < KK) {
        snode[t] = b * NPGc + id[t];
        sw[t]    = tanhf(s[t]);
    }
    __syncthreads();
    // pool: col = t&255, quarter = t>>8 handles 125 selected rows
    int col = t & 255;
    int q4 = t >> 8;
    float m = -FLT_MAX;
    for (int q = q4 * 125; q < q4 * 125 + 125; ++q) {
        float v = h2[snode[q] * HH + col] * sw[q];
        m = fmaxf(m, v);
    }
    __syncthreads();          // s[] reuse
    s[q4 * 256 + col] = m;
    __syncthreads();
    if (t < 256) {
        float r = fmaxf(fmaxf(s[t], s[256 + t]), fmaxf(s[512 + t], s[768 + t]));
        if (f32) ((float*)out)[b * HH + t] = r;
        else     ((bf16*)out)[b * HH + t] = __float2bfloat16(r);
    }
}

// ---------------- launch ----------------

extern "C" void kernel_launch(void* const* d_in, const int* in_sizes, int n_in,
                              void* d_out, int out_size, void* d_ws, size_t ws_size,
                              hipStream_t stream) {
    const int*  x    = (const int*)d_in[0];
    const int*  esrc = (const int*)d_in[1];
    const int*  edst = esrc + EE;
    const void* W1   = d_in[3];
    const void* b1   = d_in[4];
    const void* W2   = d_in[5];
    const void* b2   = d_in[6];
    const void* Wrel = d_in[7];
    const void* brel = d_in[8];
    const void* Wroot= d_in[9];

    char* w = (char*)d_ws;
    size_t off = 0;
    auto carve = [&](size_t bytes) -> void* {
        void* p = w + off;
        off = (off + bytes + 255) & ~(size_t)255;
        return p;
    };
    int*   flag    = (int*)  carve(256);
    int*   deg     = (int*)  carve((size_t)2 * NN * 4); // deg + cursor in ONE
    int*   cursor  = deg + NN;                          // carve: memset covers both
    int*   partial = (int*)  carve((size_t)NN * 4);
    int*   bsums   = (int*)  carve(256 * 4);
    int*   offsets = (int*)  carve((size_t)(NN + 1) * 4);
    int*   eidx    = (int*)  carve((size_t)EE * 4);
    float* dinv    = (float*)carve((size_t)NN * 4);
    float* trel    = (float*)carve((size_t)NN * 4);
    float* troot   = (float*)carve((size_t)NN * 4);
    float* bufA    = (float*)carve((size_t)NN * HH * 4);  // h1
    float* bufB    = (float*)carve((size_t)NN * HH * 4);  // h2
    (void)ws_size; (void)in_sizes; (void)n_in; (void)out_size;

    const int NB   = (NN + 255) / 256;     // 196
    const int EBLK = (EE + 255) / 256;     // 1172
    const int NGB  = (NN + 3) / 4;         // 12500

    hipMemsetAsync(deg, 0, (size_t)2 * NN * 4, stream);  // deg + cursor exactly
    k_count     <<<EBLK + 1, 256, 0, stream>>>(edst, deg, (const unsigned int*)W1, flag);
    k_scan_block<<<NB, 256, 0, stream>>>(deg, partial, bsums);
    k_finalize  <<<NB, 256, 0, stream>>>(deg, partial, bsums, offsets, dinv);
    k_fill      <<<EBLK, 256, 0, stream>>>(esrc, edst, offsets, cursor, eidx);

    k_layer1    <<<NGB, 256, 0, stream>>>(x, offsets, eidx, dinv, W1, b1, flag, bufA);
    k_gemm2     <<<(NN + GR - 1) / GR, 256, 0, stream>>>(offsets, eidx, dinv, bufA,
                                                         W2, b2, Wrel, Wroot, flag,
                                                         bufB, trel, troot);
    k_topk      <<<BB, 1024, 0, stream>>>(offsets, eidx, trel, troot, brel, flag,
                                          bufB, d_out);
}

// Round 12
// 295.937 us; speedup vs baseline: 1.0480x; 1.0480x over previous
//
#include <hip/hip_runtime.h>
#include <hip/hip_bf16.h>
#include <float.h>
#include <math.h>

#define NN   50000
#define BB   50
#define NPGc 1000
#define EE   300000
#define HH   256
#define FIN  79
#define KK   500
#define GR   32      // gemm rows per block

typedef __hip_bfloat16 bf16;
typedef float v2f __attribute__((ext_vector_type(2)));

__device__ __forceinline__ float bfbits(unsigned short h) {
    return __uint_as_float(((unsigned int)h) << 16);
}
__device__ __forceinline__ float ldf(const void* p, int i, bool f32) {
    return f32 ? ((const float*)p)[i] : bfbits(((const unsigned short*)p)[i]);
}
__device__ __forceinline__ float4 ldf4(const void* p, int i, bool f32) {
    if (f32) return ((const float4*)p)[i >> 2];
    ushort4 u = ((const ushort4*)p)[i >> 2];
    return make_float4(bfbits(u.x), bfbits(u.y), bfbits(u.z), bfbits(u.w));
}
// lane -> whole-wave broadcast via readlane (VALU/SALU, no LDS pipe; q is scalar)
__device__ __forceinline__ int   rli(int v, int q) {
    return __builtin_amdgcn_readlane(v, q);
}
__device__ __forceinline__ float rlf(float v, int q) {
    return __int_as_float(__builtin_amdgcn_readlane(__float_as_int(v), q));
}

// ---------------- count (+ dtype detect in the extra block) ----------------
// detect: first 10112 uint32 of W1 (40448 B, safe in both layouts). bf16-packed:
// low half is |w|<1 -> exp<128. fp32: low 16 bits are mantissa noise -> exp>=128
// about half the time.

__global__ void k_count(const int* __restrict__ edst, int* __restrict__ deg,
                        const unsigned int* __restrict__ w1, int* __restrict__ flag) {
    int t = threadIdx.x;
    if (blockIdx.x == gridDim.x - 1) {
        __shared__ int sm[256];
        int c = 0;
        for (int i = t; i < 10112; i += 256) {
            unsigned int e = (w1[i] >> 7) & 0xFFu;
            c += (e >= 128u) ? 1 : 0;
        }
        sm[t] = c;
        __syncthreads();
        for (int off = 128; off > 0; off >>= 1) {
            if (t < off) sm[t] += sm[t + off];
            __syncthreads();
        }
        if (t == 0) flag[0] = (sm[0] > 500) ? 1 : 0;
        return;
    }
    int e = blockIdx.x * 256 + t;
    if (e < EE) atomicAdd(&deg[edst[e]], 1);
}

// ---------------- CSR scan ----------------

__global__ void k_scan_block(const int* __restrict__ deg, int* __restrict__ partial,
                             int* __restrict__ bsums) {
    __shared__ int sm[256];
    int t = threadIdx.x;
    int i = blockIdx.x * 256 + t;
    int v = (i < NN) ? deg[i] : 0;
    sm[t] = v;
    __syncthreads();
    for (int off = 1; off < 256; off <<= 1) {
        int u = (t >= off) ? sm[t - off] : 0;
        __syncthreads();
        sm[t] += u;
        __syncthreads();
    }
    if (i < NN) partial[i] = sm[t];
    if (t == 255) bsums[blockIdx.x] = sm[255];
}

// finalize, with inline reduction of bsums[0..b) (grid=196 <= 256 threads)
__global__ void k_finalize(const int* __restrict__ deg, const int* __restrict__ partial,
                           const int* __restrict__ bsums, int* __restrict__ offsets,
                           float* __restrict__ dinv) {
    __shared__ int sm[256];
    int b = blockIdx.x;
    int t = threadIdx.x;
    sm[t] = (t < b) ? bsums[t] : 0;
    __syncthreads();
    for (int off = 128; off > 0; off >>= 1) {
        if (t < off) sm[t] += sm[t + off];
        __syncthreads();
    }
    int base = sm[0];
    int i = b * 256 + t;
    if (i >= NN) return;
    int incl = partial[i] + base;
    offsets[i] = incl - deg[i];
    if (i == NN - 1) offsets[NN] = incl;
    dinv[i] = rsqrtf((float)(deg[i] + 1));   // +1 self-loop
}

__global__ void k_fill(const int* __restrict__ esrc, const int* __restrict__ edst,
                       const int* __restrict__ offsets, int* __restrict__ cursor,
                       int* __restrict__ eidx) {
    int e = blockIdx.x * blockDim.x + threadIdx.x;
    if (e < EE) {
        int d = edst[e];
        int pos = atomicAdd(&cursor[d], 1);
        eidx[offsets[d] + pos] = esrc[e];
    }
}

// ---------------- layer 1: h1 = relu(GCN(one_hot(x), W1, b1)) ----------------
// Wave-per-node; lane-parallel metadata prefetch, readlane broadcast, and a
// 4-wide load pipeline (4 independent W1-row loads in flight per FMA group).

__global__ __launch_bounds__(256) void k_layer1(
        const int* __restrict__ x, const int* __restrict__ offsets,
        const int* __restrict__ eidx, const float* __restrict__ dinv,
        const void* __restrict__ W1, const void* __restrict__ b1,
        const int* __restrict__ flag, float* __restrict__ h1) {
    bool f32 = (*flag != 0);
    int node = blockIdx.x * 4 + (threadIdx.x >> 6);
    int lane = threadIdx.x & 63;
    int ch = lane * 4;
    if (node >= NN) return;
    int beg = offsets[node], end = offsets[node + 1];
    float4 acc = make_float4(0.f, 0.f, 0.f, 0.f);
    for (int base = beg; base < end; base += 64) {
        int cnt = min(64, end - base);
        int p  = base + ((lane < cnt) ? lane : 0);
        int sl = eidx[p];
        int xl = x[sl];
        float dvl = dinv[sl];
        int q = 0;
        for (; q + 4 <= cnt; q += 4) {
            int x0 = rli(xl, q), x1 = rli(xl, q + 1);
            int x2 = rli(xl, q + 2), x3 = rli(xl, q + 3);
            float d0 = rlf(dvl, q), d1 = rlf(dvl, q + 1);
            float d2 = rlf(dvl, q + 2), d3 = rlf(dvl, q + 3);
            float4 w0 = ldf4(W1, x0 * HH + ch, f32);
            float4 w1 = ldf4(W1, x1 * HH + ch, f32);
            float4 w2 = ldf4(W1, x2 * HH + ch, f32);
            float4 w3 = ldf4(W1, x3 * HH + ch, f32);
            acc.x += d0 * w0.x; acc.y += d0 * w0.y; acc.z += d0 * w0.z; acc.w += d0 * w0.w;
            acc.x += d1 * w1.x; acc.y += d1 * w1.y; acc.z += d1 * w1.z; acc.w += d1 * w1.w;
            acc.x += d2 * w2.x; acc.y += d2 * w2.y; acc.z += d2 * w2.z; acc.w += d2 * w2.w;
            acc.x += d3 * w3.x; acc.y += d3 * w3.y; acc.z += d3 * w3.z; acc.w += d3 * w3.w;
        }
        for (; q < cnt; ++q) {
            int xs   = rli(xl, q);
            float dv = rlf(dvl, q);
            float4 w = ldf4(W1, xs * HH + ch, f32);
            acc.x += dv * w.x; acc.y += dv * w.y; acc.z += dv * w.z; acc.w += dv * w.w;
        }
    }
    float di = dinv[node];
    float d2 = di * di;
    float4 ws = ldf4(W1, x[node] * HH + ch, f32);
    float4 bb = ldf4(b1, ch, f32);
    float4 o;
    o.x = fmaxf(di * acc.x + d2 * ws.x + bb.x, 0.f);
    o.y = fmaxf(di * acc.y + d2 * ws.y + bb.y, 0.f);
    o.z = fmaxf(di * acc.z + d2 * ws.z + bb.z, 0.f);
    o.w = fmaxf(di * acc.w + d2 * ws.w + bb.w, 0.f);
    ((float4*)h1)[(node * HH + ch) >> 2] = o;
}

// ---------------- fused agg2 + gemm2: h2 = relu((A_norm @ h1) @ W2 + b2) ----------
// Each block owns 32 rows. STAGE: each wave gathers its own 8 agg2 rows into its
// private slice of the LDS A-tile — readlane broadcast + 4-wide load pipeline.
// NO barrier after staging: tile is wave-private (wave rg writes AND reads only
// rows rg*8..rg*8+7; same-wave LDS RAW ordered via lgkmcnt), so each wave starts
// its FMA loop immediately. COMPUTE: W2 streamed from global with one-group
// prefetch, float2 ext-vector accumulate (v_pk_fma_f32).
// XCD swizzle: 1563 = 8*195 + 3; b<1560 -> (b&7)*195+(b>>3), tail identity.

__global__ __launch_bounds__(256) void k_gemm2(
        const int* __restrict__ offsets, const int* __restrict__ eidx,
        const float* __restrict__ dinv, const float* __restrict__ h1,
        const void* __restrict__ W2, const void* __restrict__ b2,
        const void* __restrict__ Wrel, const void* __restrict__ Wroot,
        const int* __restrict__ flag,
        float* __restrict__ Y, float* __restrict__ trel, float* __restrict__ troot) {
    __shared__ float As[GR][HH];     // 32 KB, no pad (broadcast reads)
    bool f32 = (*flag != 0);
    int t = threadIdx.x;
    int c4 = t & 63;          // float4 column index: cols 4*c4 .. 4*c4+3
    int rg = t >> 6;          // wave id -> rows rg*8 .. rg*8+7
    int b = blockIdx.x;
    int grp = (b < 1560) ? ((b & 7) * 195 + (b >> 3)) : b;
    int r0 = grp * GR;
    int lane = t & 63;
    int ch = lane * 4;
    const float4* H4 = (const float4*)h1;

    // ---- stage: gather this wave's 8 agg2 rows into As (wave-private) ----
    for (int rr = 0; rr < 8; ++rr) {
        int row = r0 + rg * 8 + rr;
        float4 acc = make_float4(0.f, 0.f, 0.f, 0.f);
        if (row < NN) {
            int beg = offsets[row], end = offsets[row + 1];
            for (int base = beg; base < end; base += 64) {
                int cnt = min(64, end - base);
                int p  = base + ((lane < cnt) ? lane : 0);
                int sl = eidx[p];
                float dvl = dinv[sl];
                int q = 0;
                for (; q + 4 <= cnt; q += 4) {
                    int s0 = rli(sl, q), s1 = rli(sl, q + 1);
                    int s2 = rli(sl, q + 2), s3 = rli(sl, q + 3);
                    float d0 = rlf(dvl, q), d1 = rlf(dvl, q + 1);
                    float d2 = rlf(dvl, q + 2), d3 = rlf(dvl, q + 3);
                    float4 v0 = H4[(s0 * HH + ch) >> 2];
                    float4 v1 = H4[(s1 * HH + ch) >> 2];
                    float4 v2 = H4[(s2 * HH + ch) >> 2];
                    float4 v3 = H4[(s3 * HH + ch) >> 2];
                    acc.x += d0 * v0.x; acc.y += d0 * v0.y; acc.z += d0 * v0.z; acc.w += d0 * v0.w;
                    acc.x += d1 * v1.x; acc.y += d1 * v1.y; acc.z += d1 * v1.z; acc.w += d1 * v1.w;
                    acc.x += d2 * v2.x; acc.y += d2 * v2.y; acc.z += d2 * v2.z; acc.w += d2 * v2.w;
                    acc.x += d3 * v3.x; acc.y += d3 * v3.y; acc.z += d3 * v3.z; acc.w += d3 * v3.w;
                }
                for (; q < cnt; ++q) {
                    int s    = rli(sl, q);
                    float dv = rlf(dvl, q);
                    float4 v = H4[(s * HH + ch) >> 2];
                    acc.x += dv * v.x; acc.y += dv * v.y;
                    acc.z += dv * v.z; acc.w += dv * v.w;
                }
            }
            float di = dinv[row];
            float d2 = di * di;
            float4 v = H4[(row * HH + ch) >> 2];
            acc.x = di * acc.x + d2 * v.x;
            acc.y = di * acc.y + d2 * v.y;
            acc.z = di * acc.z + d2 * v.z;
            acc.w = di * acc.w + d2 * v.w;
        }
        *(float4*)&As[rg * 8 + rr][ch] = acc;
    }
    // no __syncthreads(): tile is wave-private; same-wave LDS RAW is ordered.

    // ---- compute ----
    v2f accL[8], accH[8];
#pragma unroll
    for (int rr = 0; rr < 8; ++rr) { accL[rr] = (v2f)0.f; accH[rr] = (v2f)0.f; }

    if (f32) {
        const float* W = (const float*)W2;
        float4 w0 = *(const float4*)&W[0 * HH + c4 * 4];
        float4 w1 = *(const float4*)&W[1 * HH + c4 * 4];
        float4 w2 = *(const float4*)&W[2 * HH + c4 * 4];
        float4 w3 = *(const float4*)&W[3 * HH + c4 * 4];
        for (int k = 0; k < 256; k += 4) {
            float4 n0, n1, n2, n3;
            int kn = (k + 4) & 255;          // wraps to 0 on last iter (harmless)
            n0 = *(const float4*)&W[(kn + 0) * HH + c4 * 4];
            n1 = *(const float4*)&W[(kn + 1) * HH + c4 * 4];
            n2 = *(const float4*)&W[(kn + 2) * HH + c4 * 4];
            n3 = *(const float4*)&W[(kn + 3) * HH + c4 * 4];
            v2f w0L = {w0.x, w0.y}, w0H = {w0.z, w0.w};
            v2f w1L = {w1.x, w1.y}, w1H = {w1.z, w1.w};
            v2f w2L = {w2.x, w2.y}, w2H = {w2.z, w2.w};
            v2f w3L = {w3.x, w3.y}, w3H = {w3.z, w3.w};
#pragma unroll
            for (int rr = 0; rr < 8; ++rr) {
                float4 a = *(const float4*)&As[rg * 8 + rr][k];
                v2f ax = a.x, ay = a.y, az = a.z, aw = a.w;
                accL[rr] += ax * w0L; accH[rr] += ax * w0H;
                accL[rr] += ay * w1L; accH[rr] += ay * w1H;
                accL[rr] += az * w2L; accH[rr] += az * w2H;
                accL[rr] += aw * w3L; accH[rr] += aw * w3H;
            }
            w0 = n0; w1 = n1; w2 = n2; w3 = n3;
        }
    } else {
        const unsigned short* W = (const unsigned short*)W2;
        ushort4 u0 = *(const ushort4*)&W[0 * HH + c4 * 4];
        ushort4 u1 = *(const ushort4*)&W[1 * HH + c4 * 4];
        ushort4 u2 = *(const ushort4*)&W[2 * HH + c4 * 4];
        ushort4 u3 = *(const ushort4*)&W[3 * HH + c4 * 4];
        for (int k = 0; k < 256; k += 4) {
            ushort4 m0, m1, m2, m3;
            int kn = (k + 4) & 255;
            m0 = *(const ushort4*)&W[(kn + 0) * HH + c4 * 4];
            m1 = *(const ushort4*)&W[(kn + 1) * HH + c4 * 4];
            m2 = *(const ushort4*)&W[(kn + 2) * HH + c4 * 4];
            m3 = *(const ushort4*)&W[(kn + 3) * HH + c4 * 4];
            v2f w0L = {bfbits(u0.x), bfbits(u0.y)}, w0H = {bfbits(u0.z), bfbits(u0.w)};
            v2f w1L = {bfbits(u1.x), bfbits(u1.y)}, w1H = {bfbits(u1.z), bfbits(u1.w)};
            v2f w2L = {bfbits(u2.x), bfbits(u2.y)}, w2H = {bfbits(u2.z), bfbits(u2.w)};
            v2f w3L = {bfbits(u3.x), bfbits(u3.y)}, w3H = {bfbits(u3.z), bfbits(u3.w)};
#pragma unroll
            for (int rr = 0; rr < 8; ++rr) {
                float4 a = *(const float4*)&As[rg * 8 + rr][k];
                v2f ax = a.x, ay = a.y, az = a.z, aw = a.w;
                accL[rr] += ax * w0L; accH[rr] += ax * w0H;
                accL[rr] += ay * w1L; accH[rr] += ay * w1H;
                accL[rr] += az * w2L; accH[rr] += az * w2H;
                accL[rr] += aw * w3L; accH[rr] += aw * w3H;
            }
            u0 = m0; u1 = m1; u2 = m2; u3 = m3;
        }
    }

    float4 bb = ldf4(b2, c4 * 4, f32);
    float4 wr = ldf4(Wrel, c4 * 4, f32);
    float4 wo = ldf4(Wroot, c4 * 4, f32);
#pragma unroll
    for (int rr = 0; rr < 8; ++rr) {
        int row = r0 + rg * 8 + rr;
        float4 y;
        y.x = fmaxf(accL[rr].x + bb.x, 0.f);
        y.y = fmaxf(accL[rr].y + bb.y, 0.f);
        y.z = fmaxf(accH[rr].x + bb.z, 0.f);
        y.w = fmaxf(accH[rr].y + bb.w, 0.f);
        if (row < NN)
            *(float4*)&Y[row * HH + c4 * 4] = y;
        float sr = y.x * wr.x + y.y * wr.y + y.z * wr.z + y.w * wr.w;
        float so = y.x * wo.x + y.y * wo.y + y.z * wo.z + y.w * wo.w;
#pragma unroll
        for (int off = 32; off > 0; off >>= 1) {
            sr += __shfl_xor(sr, off, 64);
            so += __shfl_xor(so, off, 64);
        }
        if (c4 == 0 && row < NN) { trel[row] = sr; troot[row] = so; }
    }
}

// ---------------- fused: score -> per-graph top-k -> tanh-weighted max-pool ------
// One block per graph, 1024 threads (one bitonic element per thread).
// Desc score, asc index = jax.lax.top_k tie-break.

__global__ __launch_bounds__(1024) void k_topk(
        const int* __restrict__ offsets, const int* __restrict__ eidx,
        const float* __restrict__ trel, const float* __restrict__ troot,
        const void* __restrict__ brel, const int* __restrict__ flag,
        const float* __restrict__ h2, void* __restrict__ out) {
    __shared__ float s[1024];
    __shared__ int   id[1024];
    __shared__ float sw[KK];
    __shared__ int   snode[KK];
    bool f32 = (*flag != 0);
    int b = blockIdx.x, t = threadIdx.x;
    float br = ldf(brel, 0, f32);
    if (t < NPGc) {
        int node = b * NPGc + t;
        float sc = br + troot[node];
        int beg = offsets[node], end = offsets[node + 1];
        for (int p = beg; p < end; ++p) sc += trel[eidx[p]];
        s[t] = sc; id[t] = t;
    } else { s[t] = -FLT_MAX; id[t] = 0x7FFFFFFF; }
    for (int k = 2; k <= 1024; k <<= 1) {
        for (int j = k >> 1; j > 0; j >>= 1) {
            __syncthreads();
            int l = t ^ j;
            if (l > t) {
                float si = s[t], sl = s[l];
                int   ii = id[t], il = id[l];
                bool iFirst = (si > sl) || (si == sl && ii < il);
                bool doSwap = ((t & k) == 0) ? (!iFirst) : iFirst;
                if (doSwap) { s[t] = sl; s[l] = si; id[t] = il; id[l] = ii; }
            }
        }
    }
    __syncthreads();
    if (t < KK) {
        snode[t] = b * NPGc + id[t];
        sw[t]    = tanhf(s[t]);
    }
    __syncthreads();
    // pool: col = t&255, quarter = t>>8 handles 125 selected rows
    int col = t & 255;
    int q4 = t >> 8;
    float m = -FLT_MAX;
    for (int q = q4 * 125; q < q4 * 125 + 125; ++q) {
        float v = h2[snode[q] * HH + col] * sw[q];
        m = fmaxf(m, v);
    }
    __syncthreads();          // s[] reuse
    s[q4 * 256 + col] = m;
    __syncthreads();
    if (t < 256) {
        float r = fmaxf(fmaxf(s[t], s[256 + t]), fmaxf(s[512 + t], s[768 + t]));
        if (f32) ((float*)out)[b * HH + t] = r;
        else     ((bf16*)out)[b * HH + t] = __float2bfloat16(r);
    }
}

// ---------------- launch ----------------

extern "C" void kernel_launch(void* const* d_in, const int* in_sizes, int n_in,
                              void* d_out, int out_size, void* d_ws, size_t ws_size,
                              hipStream_t stream) {
    const int*  x    = (const int*)d_in[0];
    const int*  esrc = (const int*)d_in[1];
    const int*  edst = esrc + EE;
    const void* W1   = d_in[3];
    const void* b1   = d_in[4];
    const void* W2   = d_in[5];
    const void* b2   = d_in[6];
    const void* Wrel = d_in[7];
    const void* brel = d_in[8];
    const void* Wroot= d_in[9];

    char* w = (char*)d_ws;
    size_t off = 0;
    auto carve = [&](size_t bytes) -> void* {
        void* p = w + off;
        off = (off + bytes + 255) & ~(size_t)255;
        return p;
    };
    int*   flag    = (int*)  carve(256);
    int*   deg     = (int*)  carve((size_t)2 * NN * 4); // deg + cursor in ONE
    int*   cursor  = deg + NN;                          // carve: memset covers both
    int*   partial = (int*)  carve((size_t)NN * 4);
    int*   bsums   = (int*)  carve(256 * 4);
    int*   offsets = (int*)  carve((size_t)(NN + 1) * 4);
    int*   eidx    = (int*)  carve((size_t)EE * 4);
    float* dinv    = (float*)carve((size_t)NN * 4);
    float* trel    = (float*)carve((size_t)NN * 4);
    float* troot   = (float*)carve((size_t)NN * 4);
    float* bufA    = (float*)carve((size_t)NN * HH * 4);  // h1
    float* bufB    = (float*)carve((size_t)NN * HH * 4);  // h2
    (void)ws_size; (void)in_sizes; (void)n_in; (void)out_size;

    const int NB   = (NN + 255) / 256;     // 196
    const int EBLK = (EE + 255) / 256;     // 1172
    const int NGB  = (NN + 3) / 4;         // 12500

    hipMemsetAsync(deg, 0, (size_t)2 * NN * 4, stream);  // deg + cursor exactly
    k_count     <<<EBLK + 1, 256, 0, stream>>>(edst, deg, (const unsigned int*)W1, flag);
    k_scan_block<<<NB, 256, 0, stream>>>(deg, partial, bsums);
    k_finalize  <<<NB, 256, 0, stream>>>(deg, partial, bsums, offsets, dinv);
    k_fill      <<<EBLK, 256, 0, stream>>>(esrc, edst, offsets, cursor, eidx);

    k_layer1    <<<NGB, 256, 0, stream>>>(x, offsets, eidx, dinv, W1, b1, flag, bufA);
    k_gemm2     <<<(NN + GR - 1) / GR, 256, 0, stream>>>(offsets, eidx, dinv, bufA,
                                                         W2, b2, Wrel, Wroot, flag,
                                                         bufB, trel, troot);
    k_topk      <<<BB, 1024, 0, stream>>>(offsets, eidx, trel, troot, brel, flag,
                                          bufB, d_out);
}

// Round 13
// 259.894 us; speedup vs baseline: 1.1934x; 1.1387x over previous
//
#include <hip/hip_runtime.h>
#include <hip/hip_bf16.h>
#include <float.h>
#include <math.h>

#define NN   50000
#define BB   50
#define NPGc 1000
#define EE   300000
#define HH   256
#define FIN  79
#define KK   500
#define GR   32      // gemm rows per block
#define APAD 264     // A-plane LDS row stride in ushorts (256 + 8 pad)

typedef __hip_bfloat16 bf16;
typedef float v2f __attribute__((ext_vector_type(2)));
typedef short short8 __attribute__((ext_vector_type(8)));
typedef float f32x4 __attribute__((ext_vector_type(4)));

__device__ __forceinline__ float bfbits(unsigned short h) {
    return __uint_as_float(((unsigned int)h) << 16);
}
__device__ __forceinline__ float ldf(const void* p, int i, bool f32) {
    return f32 ? ((const float*)p)[i] : bfbits(((const unsigned short*)p)[i]);
}
__device__ __forceinline__ float4 ldf4(const void* p, int i, bool f32) {
    if (f32) return ((const float4*)p)[i >> 2];
    ushort4 u = ((const ushort4*)p)[i >> 2];
    return make_float4(bfbits(u.x), bfbits(u.y), bfbits(u.z), bfbits(u.w));
}
__device__ __forceinline__ int   rli(int v, int q) {
    return __builtin_amdgcn_readlane(v, q);
}
__device__ __forceinline__ float rlf(float v, int q) {
    return __int_as_float(__builtin_amdgcn_readlane(__float_as_int(v), q));
}
// fp32 -> 3 bf16 planes (RNE at each step; residuals exact) ~2^-24 total error
__device__ __forceinline__ void split3(float a, unsigned short& h,
                                       unsigned short& m, unsigned short& l) {
    unsigned int u = __float_as_uint(a);
    h = (unsigned short)((u + 0x7FFFu + ((u >> 16) & 1u)) >> 16);
    float r1 = a - bfbits(h);
    u = __float_as_uint(r1);
    m = (unsigned short)((u + 0x7FFFu + ((u >> 16) & 1u)) >> 16);
    float r2 = r1 - bfbits(m);
    u = __float_as_uint(r2);
    l = (unsigned short)((u + 0x7FFFu + ((u >> 16) & 1u)) >> 16);
}

// ---------------- count (+ dtype detect in the extra block) ----------------

__global__ void k_count(const int* __restrict__ edst, int* __restrict__ deg,
                        const unsigned int* __restrict__ w1, int* __restrict__ flag) {
    int t = threadIdx.x;
    if (blockIdx.x == gridDim.x - 1) {
        __shared__ int sm[256];
        int c = 0;
        for (int i = t; i < 10112; i += 256) {
            unsigned int e = (w1[i] >> 7) & 0xFFu;
            c += (e >= 128u) ? 1 : 0;
        }
        sm[t] = c;
        __syncthreads();
        for (int off = 128; off > 0; off >>= 1) {
            if (t < off) sm[t] += sm[t + off];
            __syncthreads();
        }
        if (t == 0) flag[0] = (sm[0] > 500) ? 1 : 0;
        return;
    }
    int e = blockIdx.x * 256 + t;
    if (e < EE) atomicAdd(&deg[edst[e]], 1);
}

// ---------------- prep: W2 -> 3 bf16 planes in B-fragment order ----------------
// B-frag for 16x16x32: lane holds B[k = quad*8 + j][n = lane&15], j=0..7.
// Layout: Bf[plane][nt][ks][lane] = 8 consecutive bf16 (16 B) -> coalesced loads.
// 8192 threads: one (nt,ks,lane) each. Only meaningful on the fp32 input path.

__global__ void k_prep(const void* __restrict__ W2, const int* __restrict__ flag,
                       short8* __restrict__ Bf) {
    if (*flag == 0) return;            // bf16-input path: unused
    const float* W = (const float*)W2;
    int g = blockIdx.x * 256 + threadIdx.x;   // 0..8191
    int lane = g & 63;
    int pair = g >> 6;                 // 0..127
    int ks = pair & 7, nt = pair >> 3;
    int quad = lane >> 4, l15 = lane & 15;
    short8 hv, mv, lv;
#pragma unroll
    for (int j = 0; j < 8; ++j) {
        float a = W[(ks * 32 + quad * 8 + j) * HH + nt * 16 + l15];
        unsigned short h, m, l;
        split3(a, h, m, l);
        hv[j] = (short)h; mv[j] = (short)m; lv[j] = (short)l;
    }
    int e = (nt * 8 + ks) * 64 + lane;
    Bf[e]         = hv;
    Bf[e + 8192]  = mv;
    Bf[e + 16384] = lv;
}

// ---------------- CSR scan ----------------

__global__ void k_scan_block(const int* __restrict__ deg, int* __restrict__ partial,
                             int* __restrict__ bsums) {
    __shared__ int sm[256];
    int t = threadIdx.x;
    int i = blockIdx.x * 256 + t;
    int v = (i < NN) ? deg[i] : 0;
    sm[t] = v;
    __syncthreads();
    for (int off = 1; off < 256; off <<= 1) {
        int u = (t >= off) ? sm[t - off] : 0;
        __syncthreads();
        sm[t] += u;
        __syncthreads();
    }
    if (i < NN) partial[i] = sm[t];
    if (t == 255) bsums[blockIdx.x] = sm[255];
}

__global__ void k_finalize(const int* __restrict__ deg, const int* __restrict__ partial,
                           const int* __restrict__ bsums, int* __restrict__ offsets,
                           float* __restrict__ dinv) {
    __shared__ int sm[256];
    int b = blockIdx.x;
    int t = threadIdx.x;
    sm[t] = (t < b) ? bsums[t] : 0;
    __syncthreads();
    for (int off = 128; off > 0; off >>= 1) {
        if (t < off) sm[t] += sm[t + off];
        __syncthreads();
    }
    int base = sm[0];
    int i = b * 256 + t;
    if (i >= NN) return;
    int incl = partial[i] + base;
    offsets[i] = incl - deg[i];
    if (i == NN - 1) offsets[NN] = incl;
    dinv[i] = rsqrtf((float)(deg[i] + 1));   // +1 self-loop
}

__global__ void k_fill(const int* __restrict__ esrc, const int* __restrict__ edst,
                       const int* __restrict__ offsets, int* __restrict__ cursor,
                       int* __restrict__ eidx) {
    int e = blockIdx.x * blockDim.x + threadIdx.x;
    if (e < EE) {
        int d = edst[e];
        int pos = atomicAdd(&cursor[d], 1);
        eidx[offsets[d] + pos] = esrc[e];
    }
}

// ---------------- layer 1: h1 = relu(GCN(one_hot(x), W1, b1)) ----------------

__global__ __launch_bounds__(256) void k_layer1(
        const int* __restrict__ x, const int* __restrict__ offsets,
        const int* __restrict__ eidx, const float* __restrict__ dinv,
        const void* __restrict__ W1, const void* __restrict__ b1,
        const int* __restrict__ flag, float* __restrict__ h1) {
    bool f32 = (*flag != 0);
    int node = blockIdx.x * 4 + (threadIdx.x >> 6);
    int lane = threadIdx.x & 63;
    int ch = lane * 4;
    if (node >= NN) return;
    int beg = offsets[node], end = offsets[node + 1];
    float4 acc = make_float4(0.f, 0.f, 0.f, 0.f);
    for (int base = beg; base < end; base += 64) {
        int cnt = min(64, end - base);
        int p  = base + ((lane < cnt) ? lane : 0);
        int sl = eidx[p];
        int xl = x[sl];
        float dvl = dinv[sl];
        int q = 0;
        for (; q + 4 <= cnt; q += 4) {
            int x0 = rli(xl, q), x1 = rli(xl, q + 1);
            int x2 = rli(xl, q + 2), x3 = rli(xl, q + 3);
            float d0 = rlf(dvl, q), d1 = rlf(dvl, q + 1);
            float d2 = rlf(dvl, q + 2), d3 = rlf(dvl, q + 3);
            float4 w0 = ldf4(W1, x0 * HH + ch, f32);
            float4 w1 = ldf4(W1, x1 * HH + ch, f32);
            float4 w2 = ldf4(W1, x2 * HH + ch, f32);
            float4 w3 = ldf4(W1, x3 * HH + ch, f32);
            acc.x += d0 * w0.x; acc.y += d0 * w0.y; acc.z += d0 * w0.z; acc.w += d0 * w0.w;
            acc.x += d1 * w1.x; acc.y += d1 * w1.y; acc.z += d1 * w1.z; acc.w += d1 * w1.w;
            acc.x += d2 * w2.x; acc.y += d2 * w2.y; acc.z += d2 * w2.z; acc.w += d2 * w2.w;
            acc.x += d3 * w3.x; acc.y += d3 * w3.y; acc.z += d3 * w3.z; acc.w += d3 * w3.w;
        }
        for (; q < cnt; ++q) {
            int xs   = rli(xl, q);
            float dv = rlf(dvl, q);
            float4 w = ldf4(W1, xs * HH + ch, f32);
            acc.x += dv * w.x; acc.y += dv * w.y; acc.z += dv * w.z; acc.w += dv * w.w;
        }
    }
    float di = dinv[node];
    float d2 = di * di;
    float4 ws = ldf4(W1, x[node] * HH + ch, f32);
    float4 bb = ldf4(b1, ch, f32);
    float4 o;
    o.x = fmaxf(di * acc.x + d2 * ws.x + bb.x, 0.f);
    o.y = fmaxf(di * acc.y + d2 * ws.y + bb.y, 0.f);
    o.z = fmaxf(di * acc.z + d2 * ws.z + bb.z, 0.f);
    o.w = fmaxf(di * acc.w + d2 * ws.w + bb.w, 0.f);
    ((float4*)h1)[(node * HH + ch) >> 2] = o;
}

// ---------------- fused agg2 + gemm2: h2 = relu((A_norm @ h1) @ W2 + b2) ----------
// fp32 path: bf16x3-split MFMA. STAGE: r12 readlane gather -> split3 -> 3 bf16
// LDS planes (row stride 264 ushorts: 2-way-free b128 reads). COMPUTE: 8 k-steps,
// per wave 2 m-tiles x 4 n-tiles, 6 split-products (hh, mh, hm, lh, hl, mm) ->
// 48 mfma_f32_16x16x32_bf16 per k-step, chain distance 8. B-frags streamed from
// the k_prep buffer (coalesced 16 B/lane, L2-resident). EPILOGUE: C/D map
// col=lane&15, row=quad*4+reg; quad-shuffle + LDS cross-wave reduce for trel/troot.
// bf16-input path: r12 pk-fma fallback (correctness only).

__global__ __launch_bounds__(256) void k_gemm2(
        const int* __restrict__ offsets, const int* __restrict__ eidx,
        const float* __restrict__ dinv, const float* __restrict__ h1,
        const void* __restrict__ W2, const void* __restrict__ b2,
        const void* __restrict__ Wrel, const void* __restrict__ Wroot,
        const int* __restrict__ flag, const short8* __restrict__ Bf,
        float* __restrict__ Y, float* __restrict__ trel, float* __restrict__ troot) {
    __shared__ __align__(16) char lds[3 * GR * APAD * 2 + 1024];  // 51712 B
    bool f32 = (*flag != 0);
    int t = threadIdx.x;
    int lane = t & 63;
    int rg = t >> 6;
    int b = blockIdx.x;
    int grp = (b < 1560) ? ((b & 7) * 195 + (b >> 3)) : b;
    int r0 = grp * GR;
    int ch = lane * 4;
    const float4* H4 = (const float4*)h1;

    if (f32) {
        unsigned short* pH = (unsigned short*)lds;
        unsigned short* pM = pH + GR * APAD;
        unsigned short* pL = pM + GR * APAD;
        float* redR = (float*)(lds + 3 * GR * APAD * 2);
        float* redO = redR + 128;

        // ---- stage: gather 8 agg2 rows per wave, split to 3 bf16 planes ----
        for (int rr = 0; rr < 8; ++rr) {
            int row = r0 + rg * 8 + rr;
            float4 acc = make_float4(0.f, 0.f, 0.f, 0.f);
            if (row < NN) {
                int beg = offsets[row], end = offsets[row + 1];
                for (int base = beg; base < end; base += 64) {
                    int cnt = min(64, end - base);
                    int p  = base + ((lane < cnt) ? lane : 0);
                    int sl = eidx[p];
                    float dvl = dinv[sl];
                    int q = 0;
                    for (; q + 4 <= cnt; q += 4) {
                        int s0 = rli(sl, q), s1 = rli(sl, q + 1);
                        int s2 = rli(sl, q + 2), s3 = rli(sl, q + 3);
                        float d0 = rlf(dvl, q), d1 = rlf(dvl, q + 1);
                        float d2 = rlf(dvl, q + 2), d3 = rlf(dvl, q + 3);
                        float4 v0 = H4[(s0 * HH + ch) >> 2];
                        float4 v1 = H4[(s1 * HH + ch) >> 2];
                        float4 v2 = H4[(s2 * HH + ch) >> 2];
                        float4 v3 = H4[(s3 * HH + ch) >> 2];
                        acc.x += d0 * v0.x; acc.y += d0 * v0.y; acc.z += d0 * v0.z; acc.w += d0 * v0.w;
                        acc.x += d1 * v1.x; acc.y += d1 * v1.y; acc.z += d1 * v1.z; acc.w += d1 * v1.w;
                        acc.x += d2 * v2.x; acc.y += d2 * v2.y; acc.z += d2 * v2.z; acc.w += d2 * v2.w;
                        acc.x += d3 * v3.x; acc.y += d3 * v3.y; acc.z += d3 * v3.z; acc.w += d3 * v3.w;
                    }
                    for (; q < cnt; ++q) {
                        int s    = rli(sl, q);
                        float dv = rlf(dvl, q);
                        float4 v = H4[(s * HH + ch) >> 2];
                        acc.x += dv * v.x; acc.y += dv * v.y;
                        acc.z += dv * v.z; acc.w += dv * v.w;
                    }
                }
                float di = dinv[row];
                float d2 = di * di;
                float4 v = H4[(row * HH + ch) >> 2];
                acc.x = di * acc.x + d2 * v.x;
                acc.y = di * acc.y + d2 * v.y;
                acc.z = di * acc.z + d2 * v.z;
                acc.w = di * acc.w + d2 * v.w;
            }
            ushort4 hv, mv, lv;
            split3(acc.x, hv.x, mv.x, lv.x);
            split3(acc.y, hv.y, mv.y, lv.y);
            split3(acc.z, hv.z, mv.z, lv.z);
            split3(acc.w, hv.w, mv.w, lv.w);
            int base = (rg * 8 + rr) * APAD + ch;
            *(ushort4*)(pH + base) = hv;
            *(ushort4*)(pM + base) = mv;
            *(ushort4*)(pL + base) = lv;
        }
        __syncthreads();   // cross-wave: A-frag reads span all 32 rows

        // ---- compute: 8 k-steps x (2 mt x 4 nt) tiles x 6 split products ----
        int quad = lane >> 4, l15 = lane & 15;
        int nt0 = rg * 4;
        f32x4 acc[2][4];
#pragma unroll
        for (int mt = 0; mt < 2; ++mt)
#pragma unroll
            for (int nt = 0; nt < 4; ++nt) acc[mt][nt] = (f32x4)0.f;

#pragma unroll
        for (int ks = 0; ks < 8; ++ks) {
            short8 aH[2], aM[2], aL[2];
#pragma unroll
            for (int mt = 0; mt < 2; ++mt) {
                int boff = (mt * 16 + l15) * APAD + ks * 32 + quad * 8;
                aH[mt] = *(const short8*)(pH + boff);
                aM[mt] = *(const short8*)(pM + boff);
                aL[mt] = *(const short8*)(pL + boff);
            }
            short8 bH[4], bM[4], bL[4];
#pragma unroll
            for (int nt = 0; nt < 4; ++nt) {
                int e = ((nt0 + nt) * 8 + ks) * 64 + lane;
                bH[nt] = Bf[e];
                bM[nt] = Bf[e + 8192];
                bL[nt] = Bf[e + 16384];
            }
#pragma unroll
            for (int mt = 0; mt < 2; ++mt)
#pragma unroll
                for (int nt = 0; nt < 4; ++nt)
                    acc[mt][nt] = __builtin_amdgcn_mfma_f32_16x16x32_bf16(aH[mt], bH[nt], acc[mt][nt], 0, 0, 0);
#pragma unroll
            for (int mt = 0; mt < 2; ++mt)
#pragma unroll
                for (int nt = 0; nt < 4; ++nt)
                    acc[mt][nt] = __builtin_amdgcn_mfma_f32_16x16x32_bf16(aM[mt], bH[nt], acc[mt][nt], 0, 0, 0);
#pragma unroll
            for (int mt = 0; mt < 2; ++mt)
#pragma unroll
                for (int nt = 0; nt < 4; ++nt)
                    acc[mt][nt] = __builtin_amdgcn_mfma_f32_16x16x32_bf16(aH[mt], bM[nt], acc[mt][nt], 0, 0, 0);
#pragma unroll
            for (int mt = 0; mt < 2; ++mt)
#pragma unroll
                for (int nt = 0; nt < 4; ++nt)
                    acc[mt][nt] = __builtin_amdgcn_mfma_f32_16x16x32_bf16(aL[mt], bH[nt], acc[mt][nt], 0, 0, 0);
#pragma unroll
            for (int mt = 0; mt < 2; ++mt)
#pragma unroll
                for (int nt = 0; nt < 4; ++nt)
                    acc[mt][nt] = __builtin_amdgcn_mfma_f32_16x16x32_bf16(aH[mt], bL[nt], acc[mt][nt], 0, 0, 0);
#pragma unroll
            for (int mt = 0; mt < 2; ++mt)
#pragma unroll
                for (int nt = 0; nt < 4; ++nt)
                    acc[mt][nt] = __builtin_amdgcn_mfma_f32_16x16x32_bf16(aM[mt], bM[nt], acc[mt][nt], 0, 0, 0);
        }

        // ---- epilogue: relu + store + fused scorer dots ----
        const float* b2f = (const float*)b2;
        const float* wrf = (const float*)Wrel;
        const float* wof = (const float*)Wroot;
        float b2v[4], wrv[4], wov[4];
#pragma unroll
        for (int nt = 0; nt < 4; ++nt) {
            int col = (nt0 + nt) * 16 + l15;
            b2v[nt] = b2f[col]; wrv[nt] = wrf[col]; wov[nt] = wof[col];
        }
#pragma unroll
        for (int mt = 0; mt < 2; ++mt) {
#pragma unroll
            for (int r = 0; r < 4; ++r) {
                int row = r0 + mt * 16 + quad * 4 + r;
                float sr = 0.f, so = 0.f;
#pragma unroll
                for (int nt = 0; nt < 4; ++nt) {
                    float y = fmaxf(acc[mt][nt][r] + b2v[nt], 0.f);
                    if (row < NN) Y[row * HH + (nt0 + nt) * 16 + l15] = y;
                    sr += y * wrv[nt];
                    so += y * wov[nt];
                }
#pragma unroll
                for (int off = 1; off < 16; off <<= 1) {
                    sr += __shfl_xor(sr, off, 64);
                    so += __shfl_xor(so, off, 64);
                }
                if (l15 == 0) {
                    redR[(mt * 16 + quad * 4 + r) * 4 + rg] = sr;
                    redO[(mt * 16 + quad * 4 + r) * 4 + rg] = so;
                }
            }
        }
        __syncthreads();
        if (t < GR) {
            int row = r0 + t;
            if (row < NN) {
                trel[row]  = redR[t * 4] + redR[t * 4 + 1] + redR[t * 4 + 2] + redR[t * 4 + 3];
                troot[row] = redO[t * 4] + redO[t * 4 + 1] + redO[t * 4 + 2] + redO[t * 4 + 3];
            }
        }
        return;
    }

    // ---------------- bf16-input fallback: r12 pk-fma path ----------------
    {
        float (*As)[HH] = (float (*)[HH])lds;
        int c4 = lane;
        for (int rr = 0; rr < 8; ++rr) {
            int row = r0 + rg * 8 + rr;
            float4 acc = make_float4(0.f, 0.f, 0.f, 0.f);
            if (row < NN) {
                int beg = offsets[row], end = offsets[row + 1];
                for (int base = beg; base < end; base += 64) {
                    int cnt = min(64, end - base);
                    int p  = base + ((lane < cnt) ? lane : 0);
                    int sl = eidx[p];
                    float dvl = dinv[sl];
                    for (int q = 0; q < cnt; ++q) {
                        int s    = rli(sl, q);
                        float dv = rlf(dvl, q);
                        float4 v = H4[(s * HH + ch) >> 2];
                        acc.x += dv * v.x; acc.y += dv * v.y;
                        acc.z += dv * v.z; acc.w += dv * v.w;
                    }
                }
                float di = dinv[row];
                float d2 = di * di;
                float4 v = H4[(row * HH + ch) >> 2];
                acc.x = di * acc.x + d2 * v.x;
                acc.y = di * acc.y + d2 * v.y;
                acc.z = di * acc.z + d2 * v.z;
                acc.w = di * acc.w + d2 * v.w;
            }
            *(float4*)&As[rg * 8 + rr][ch] = acc;
        }
        // no barrier: tile slice is wave-private

        v2f accL[8], accH[8];
#pragma unroll
        for (int rr = 0; rr < 8; ++rr) { accL[rr] = (v2f)0.f; accH[rr] = (v2f)0.f; }
        const unsigned short* W = (const unsigned short*)W2;
        ushort4 u0 = *(const ushort4*)&W[0 * HH + c4 * 4];
        ushort4 u1 = *(const ushort4*)&W[1 * HH + c4 * 4];
        ushort4 u2 = *(const ushort4*)&W[2 * HH + c4 * 4];
        ushort4 u3 = *(const ushort4*)&W[3 * HH + c4 * 4];
        for (int k = 0; k < 256; k += 4) {
            ushort4 m0, m1, m2, m3;
            int kn = (k + 4) & 255;
            m0 = *(const ushort4*)&W[(kn + 0) * HH + c4 * 4];
            m1 = *(const ushort4*)&W[(kn + 1) * HH + c4 * 4];
            m2 = *(const ushort4*)&W[(kn + 2) * HH + c4 * 4];
            m3 = *(const ushort4*)&W[(kn + 3) * HH + c4 * 4];
            v2f w0L = {bfbits(u0.x), bfbits(u0.y)}, w0H = {bfbits(u0.z), bfbits(u0.w)};
            v2f w1L = {bfbits(u1.x), bfbits(u1.y)}, w1H = {bfbits(u1.z), bfbits(u1.w)};
            v2f w2L = {bfbits(u2.x), bfbits(u2.y)}, w2H = {bfbits(u2.z), bfbits(u2.w)};
            v2f w3L = {bfbits(u3.x), bfbits(u3.y)}, w3H = {bfbits(u3.z), bfbits(u3.w)};
#pragma unroll
            for (int rr = 0; rr < 8; ++rr) {
                float4 a = *(const float4*)&As[rg * 8 + rr][k];
                v2f ax = a.x, ay = a.y, az = a.z, aw = a.w;
                accL[rr] += ax * w0L; accH[rr] += ax * w0H;
                accL[rr] += ay * w1L; accH[rr] += ay * w1H;
                accL[rr] += az * w2L; accH[rr] += az * w2H;
                accL[rr] += aw * w3L; accH[rr] += aw * w3H;
            }
            u0 = m0; u1 = m1; u2 = m2; u3 = m3;
        }
        float4 bb = ldf4(b2, c4 * 4, f32);
        float4 wr = ldf4(Wrel, c4 * 4, f32);
        float4 wo = ldf4(Wroot, c4 * 4, f32);
#pragma unroll
        for (int rr = 0; rr < 8; ++rr) {
            int row = r0 + rg * 8 + rr;
            float4 y;
            y.x = fmaxf(accL[rr].x + bb.x, 0.f);
            y.y = fmaxf(accL[rr].y + bb.y, 0.f);
            y.z = fmaxf(accH[rr].x + bb.z, 0.f);
            y.w = fmaxf(accH[rr].y + bb.w, 0.f);
            if (row < NN)
                *(float4*)&Y[row * HH + c4 * 4] = y;
            float sr = y.x * wr.x + y.y * wr.y + y.z * wr.z + y.w * wr.w;
            float so = y.x * wo.x + y.y * wo.y + y.z * wo.z + y.w * wo.w;
#pragma unroll
            for (int off = 32; off > 0; off >>= 1) {
                sr += __shfl_xor(sr, off, 64);
                so += __shfl_xor(so, off, 64);
            }
            if (c4 == 0 && row < NN) { trel[row] = sr; troot[row] = so; }
        }
    }
}

// ---------------- fused: score -> per-graph top-k -> tanh-weighted max-pool ------

__global__ __launch_bounds__(1024) void k_topk(
        const int* __restrict__ offsets, const int* __restrict__ eidx,
        const float* __restrict__ trel, const float* __restrict__ troot,
        const void* __restrict__ brel, const int* __restrict__ flag,
        const float* __restrict__ h2, void* __restrict__ out) {
    __shared__ float s[1024];
    __shared__ int   id[1024];
    __shared__ float sw[KK];
    __shared__ int   snode[KK];
    bool f32 = (*flag != 0);
    int b = blockIdx.x, t = threadIdx.x;
    float br = ldf(brel, 0, f32);
    if (t < NPGc) {
        int node = b * NPGc + t;
        float sc = br + troot[node];
        int beg = offsets[node], end = offsets[node + 1];
        for (int p = beg; p < end; ++p) sc += trel[eidx[p]];
        s[t] = sc; id[t] = t;
    } else { s[t] = -FLT_MAX; id[t] = 0x7FFFFFFF; }
    for (int k = 2; k <= 1024; k <<= 1) {
        for (int j = k >> 1; j > 0; j >>= 1) {
            __syncthreads();
            int l = t ^ j;
            if (l > t) {
                float si = s[t], sl = s[l];
                int   ii = id[t], il = id[l];
                bool iFirst = (si > sl) || (si == sl && ii < il);
                bool doSwap = ((t & k) == 0) ? (!iFirst) : iFirst;
                if (doSwap) { s[t] = sl; s[l] = si; id[t] = il; id[l] = ii; }
            }
        }
    }
    __syncthreads();
    if (t < KK) {
        snode[t] = b * NPGc + id[t];
        sw[t]    = tanhf(s[t]);
    }
    __syncthreads();
    int col = t & 255;
    int q4 = t >> 8;
    float m = -FLT_MAX;
    for (int q = q4 * 125; q < q4 * 125 + 125; ++q) {
        float v = h2[snode[q] * HH + col] * sw[q];
        m = fmaxf(m, v);
    }
    __syncthreads();          // s[] reuse
    s[q4 * 256 + col] = m;
    __syncthreads();
    if (t < 256) {
        float r = fmaxf(fmaxf(s[t], s[256 + t]), fmaxf(s[512 + t], s[768 + t]));
        if (f32) ((float*)out)[b * HH + t] = r;
        else     ((bf16*)out)[b * HH + t] = __float2bfloat16(r);
    }
}

// ---------------- launch ----------------

extern "C" void kernel_launch(void* const* d_in, const int* in_sizes, int n_in,
                              void* d_out, int out_size, void* d_ws, size_t ws_size,
                              hipStream_t stream) {
    const int*  x    = (const int*)d_in[0];
    const int*  esrc = (const int*)d_in[1];
    const int*  edst = esrc + EE;
    const void* W1   = d_in[3];
    const void* b1   = d_in[4];
    const void* W2   = d_in[5];
    const void* b2   = d_in[6];
    const void* Wrel = d_in[7];
    const void* brel = d_in[8];
    const void* Wroot= d_in[9];

    char* w = (char*)d_ws;
    size_t off = 0;
    auto carve = [&](size_t bytes) -> void* {
        void* p = w + off;
        off = (off + bytes + 255) & ~(size_t)255;
        return p;
    };
    int*    flag    = (int*)   carve(256);
    int*    deg     = (int*)   carve((size_t)2 * NN * 4); // deg + cursor contiguous
    int*    cursor  = deg + NN;
    int*    partial = (int*)   carve((size_t)NN * 4);
    int*    bsums   = (int*)   carve(256 * 4);
    int*    offsets = (int*)   carve((size_t)(NN + 1) * 4);
    int*    eidx    = (int*)   carve((size_t)EE * 4);
    float*  dinv    = (float*) carve((size_t)NN * 4);
    float*  trel    = (float*) carve((size_t)NN * 4);
    float*  troot   = (float*) carve((size_t)NN * 4);
    short8* Bf      = (short8*)carve((size_t)3 * 8192 * 16);  // W2 bf16x3 B-frags
    float*  bufA    = (float*) carve((size_t)NN * HH * 4);    // h1
    float*  bufB    = (float*) carve((size_t)NN * HH * 4);    // h2
    (void)ws_size; (void)in_sizes; (void)n_in; (void)out_size;

    const int NB   = (NN + 255) / 256;     // 196
    const int EBLK = (EE + 255) / 256;     // 1172
    const int NGB  = (NN + 3) / 4;         // 12500

    hipMemsetAsync(deg, 0, (size_t)2 * NN * 4, stream);  // deg + cursor exactly
    k_count     <<<EBLK + 1, 256, 0, stream>>>(edst, deg, (const unsigned int*)W1, flag);
    k_prep      <<<32, 256, 0, stream>>>(W2, flag, Bf);
    k_scan_block<<<NB, 256, 0, stream>>>(deg, partial, bsums);
    k_finalize  <<<NB, 256, 0, stream>>>(deg, partial, bsums, offsets, dinv);
    k_fill      <<<EBLK, 256, 0, stream>>>(esrc, edst, offsets, cursor, eidx);

    k_layer1    <<<NGB, 256, 0, stream>>>(x, offsets, eidx, dinv, W1, b1, flag, bufA);
    k_gemm2     <<<(NN + GR - 1) / GR, 256, 0, stream>>>(offsets, eidx, dinv, bufA,
                                                         W2, b2, Wrel, Wroot, flag,
                                                         Bf, bufB, trel, troot);
    k_topk      <<<BB, 1024, 0, stream>>>(offsets, eidx, trel, troot, brel, flag,
                                          bufB, d_out);
}

// Round 14
// 233.281 us; speedup vs baseline: 1.3295x; 1.1141x over previous
//
#include <hip/hip_runtime.h>
#include <hip/hip_bf16.h>
#include <float.h>
#include <math.h>

#define NN   50000
#define BB   50
#define NPGc 1000
#define EE   300000
#define HH   256
#define FIN  79
#define KK   500
#define GR   32      // gemm rows per block
#define APAD 264     // A-plane LDS row stride in ushorts (256 + 8 pad)

typedef __hip_bfloat16 bf16;
typedef float v2f __attribute__((ext_vector_type(2)));
typedef short short8 __attribute__((ext_vector_type(8)));
typedef float f32x4 __attribute__((ext_vector_type(4)));

__device__ __forceinline__ float bfbits(unsigned short h) {
    return __uint_as_float(((unsigned int)h) << 16);
}
__device__ __forceinline__ float ldf(const void* p, int i, bool f32) {
    return f32 ? ((const float*)p)[i] : bfbits(((const unsigned short*)p)[i]);
}
__device__ __forceinline__ float4 ldf4(const void* p, int i, bool f32) {
    if (f32) return ((const float4*)p)[i >> 2];
    ushort4 u = ((const ushort4*)p)[i >> 2];
    return make_float4(bfbits(u.x), bfbits(u.y), bfbits(u.z), bfbits(u.w));
}
__device__ __forceinline__ int   rli(int v, int q) {
    return __builtin_amdgcn_readlane(v, q);
}
__device__ __forceinline__ float rlf(float v, int q) {
    return __int_as_float(__builtin_amdgcn_readlane(__float_as_int(v), q));
}
// fp32 -> 3 bf16 planes (RNE at each step; residuals exact) ~2^-24 total error
__device__ __forceinline__ void split3(float a, unsigned short& h,
                                       unsigned short& m, unsigned short& l) {
    unsigned int u = __float_as_uint(a);
    h = (unsigned short)((u + 0x7FFFu + ((u >> 16) & 1u)) >> 16);
    float r1 = a - bfbits(h);
    u = __float_as_uint(r1);
    m = (unsigned short)((u + 0x7FFFu + ((u >> 16) & 1u)) >> 16);
    float r2 = r1 - bfbits(m);
    u = __float_as_uint(r2);
    l = (unsigned short)((u + 0x7FFFu + ((u >> 16) & 1u)) >> 16);
}

// ---------------- count (+ dtype detect in the extra block) ----------------
// Also records each edge's intra-bucket position so k_fill needs no atomics.

__global__ void k_count(const int* __restrict__ edst, int* __restrict__ deg,
                        int* __restrict__ pose,
                        const unsigned int* __restrict__ w1, int* __restrict__ flag) {
    int t = threadIdx.x;
    if (blockIdx.x == gridDim.x - 1) {
        __shared__ int sm[256];
        int c = 0;
        for (int i = t; i < 10112; i += 256) {
            unsigned int e = (w1[i] >> 7) & 0xFFu;
            c += (e >= 128u) ? 1 : 0;
        }
        sm[t] = c;
        __syncthreads();
        for (int off = 128; off > 0; off >>= 1) {
            if (t < off) sm[t] += sm[t + off];
            __syncthreads();
        }
        if (t == 0) flag[0] = (sm[0] > 500) ? 1 : 0;
        return;
    }
    int e = blockIdx.x * 256 + t;
    if (e < EE) pose[e] = atomicAdd(&deg[edst[e]], 1);
}

// ---------------- prep: W2 -> 3 bf16 planes in B-fragment order ----------------

__global__ void k_prep(const void* __restrict__ W2, const int* __restrict__ flag,
                       short8* __restrict__ Bf) {
    if (*flag == 0) return;            // bf16-input path: unused
    const float* W = (const float*)W2;
    int g = blockIdx.x * 256 + threadIdx.x;   // 0..8191
    int lane = g & 63;
    int pair = g >> 6;                 // 0..127
    int ks = pair & 7, nt = pair >> 3;
    int quad = lane >> 4, l15 = lane & 15;
    short8 hv, mv, lv;
#pragma unroll
    for (int j = 0; j < 8; ++j) {
        float a = W[(ks * 32 + quad * 8 + j) * HH + nt * 16 + l15];
        unsigned short h, m, l;
        split3(a, h, m, l);
        hv[j] = (short)h; mv[j] = (short)m; lv[j] = (short)l;
    }
    int e = (nt * 8 + ks) * 64 + lane;
    Bf[e]         = hv;
    Bf[e + 8192]  = mv;
    Bf[e + 16384] = lv;
}

// ---------------- CSR scan ----------------

__global__ void k_scan_block(const int* __restrict__ deg, int* __restrict__ partial,
                             int* __restrict__ bsums) {
    __shared__ int sm[256];
    int t = threadIdx.x;
    int i = blockIdx.x * 256 + t;
    int v = (i < NN) ? deg[i] : 0;
    sm[t] = v;
    __syncthreads();
    for (int off = 1; off < 256; off <<= 1) {
        int u = (t >= off) ? sm[t - off] : 0;
        __syncthreads();
        sm[t] += u;
        __syncthreads();
    }
    if (i < NN) partial[i] = sm[t];
    if (t == 255) bsums[blockIdx.x] = sm[255];
}

__global__ void k_finalize(const int* __restrict__ deg, const int* __restrict__ partial,
                           const int* __restrict__ bsums, int* __restrict__ offsets,
                           float* __restrict__ dinv) {
    __shared__ int sm[256];
    int b = blockIdx.x;
    int t = threadIdx.x;
    sm[t] = (t < b) ? bsums[t] : 0;
    __syncthreads();
    for (int off = 128; off > 0; off >>= 1) {
        if (t < off) sm[t] += sm[t + off];
        __syncthreads();
    }
    int base = sm[0];
    int i = b * 256 + t;
    if (i >= NN) return;
    int incl = partial[i] + base;
    offsets[i] = incl - deg[i];
    if (i == NN - 1) offsets[NN] = incl;
    dinv[i] = rsqrtf((float)(deg[i] + 1));   // +1 self-loop
}

__global__ void k_fill(const int* __restrict__ esrc, const int* __restrict__ edst,
                       const int* __restrict__ offsets, const int* __restrict__ pose,
                       int* __restrict__ eidx) {
    int e = blockIdx.x * blockDim.x + threadIdx.x;
    if (e < EE) {
        int d = edst[e];
        eidx[offsets[d] + pose[e]] = esrc[e];
    }
}

// ---------------- layer 1: h1 = relu(GCN(one_hot(x), W1, b1)) ----------------

__global__ __launch_bounds__(256) void k_layer1(
        const int* __restrict__ x, const int* __restrict__ offsets,
        const int* __restrict__ eidx, const float* __restrict__ dinv,
        const void* __restrict__ W1, const void* __restrict__ b1,
        const int* __restrict__ flag, float* __restrict__ h1) {
    bool f32 = (*flag != 0);
    int node = blockIdx.x * 4 + (threadIdx.x >> 6);
    int lane = threadIdx.x & 63;
    int ch = lane * 4;
    if (node >= NN) return;
    int beg = offsets[node], end = offsets[node + 1];
    float4 acc = make_float4(0.f, 0.f, 0.f, 0.f);
    for (int base = beg; base < end; base += 64) {
        int cnt = min(64, end - base);
        int p  = base + ((lane < cnt) ? lane : 0);
        int sl = eidx[p];
        int xl = x[sl];
        float dvl = dinv[sl];
        int q = 0;
        for (; q + 4 <= cnt; q += 4) {
            int x0 = rli(xl, q), x1 = rli(xl, q + 1);
            int x2 = rli(xl, q + 2), x3 = rli(xl, q + 3);
            float d0 = rlf(dvl, q), d1 = rlf(dvl, q + 1);
            float d2 = rlf(dvl, q + 2), d3 = rlf(dvl, q + 3);
            float4 w0 = ldf4(W1, x0 * HH + ch, f32);
            float4 w1 = ldf4(W1, x1 * HH + ch, f32);
            float4 w2 = ldf4(W1, x2 * HH + ch, f32);
            float4 w3 = ldf4(W1, x3 * HH + ch, f32);
            acc.x += d0 * w0.x; acc.y += d0 * w0.y; acc.z += d0 * w0.z; acc.w += d0 * w0.w;
            acc.x += d1 * w1.x; acc.y += d1 * w1.y; acc.z += d1 * w1.z; acc.w += d1 * w1.w;
            acc.x += d2 * w2.x; acc.y += d2 * w2.y; acc.z += d2 * w2.z; acc.w += d2 * w2.w;
            acc.x += d3 * w3.x; acc.y += d3 * w3.y; acc.z += d3 * w3.z; acc.w += d3 * w3.w;
        }
        for (; q < cnt; ++q) {
            int xs   = rli(xl, q);
            float dv = rlf(dvl, q);
            float4 w = ldf4(W1, xs * HH + ch, f32);
            acc.x += dv * w.x; acc.y += dv * w.y; acc.z += dv * w.z; acc.w += dv * w.w;
        }
    }
    float di = dinv[node];
    float d2 = di * di;
    float4 ws = ldf4(W1, x[node] * HH + ch, f32);
    float4 bb = ldf4(b1, ch, f32);
    float4 o;
    o.x = fmaxf(di * acc.x + d2 * ws.x + bb.x, 0.f);
    o.y = fmaxf(di * acc.y + d2 * ws.y + bb.y, 0.f);
    o.z = fmaxf(di * acc.z + d2 * ws.z + bb.z, 0.f);
    o.w = fmaxf(di * acc.w + d2 * ws.w + bb.w, 0.f);
    ((float4*)h1)[(node * HH + ch) >> 2] = o;
}

// ---------------- fused agg2 + gemm2: h2 = relu((A_norm @ h1) @ W2 + b2) ----------
// fp32 path: bf16x3-split MFMA (r13). r14 delta: the 8 rows' edge metadata
// (offsets, first-chunk eidx, dinv) is preloaded in BATCHED independent loads
// before the per-row gather loops, collapsing 16 serial load-chains into ~2.

__global__ __launch_bounds__(256) void k_gemm2(
        const int* __restrict__ offsets, const int* __restrict__ eidx,
        const float* __restrict__ dinv, const float* __restrict__ h1,
        const void* __restrict__ W2, const void* __restrict__ b2,
        const void* __restrict__ Wrel, const void* __restrict__ Wroot,
        const int* __restrict__ flag, const short8* __restrict__ Bf,
        float* __restrict__ Y, float* __restrict__ trel, float* __restrict__ troot) {
    __shared__ __align__(16) char lds[3 * GR * APAD * 2 + 1024];  // 51712 B
    bool f32 = (*flag != 0);
    int t = threadIdx.x;
    int lane = t & 63;
    int rg = t >> 6;
    int b = blockIdx.x;
    int grp = (b < 1560) ? ((b & 7) * 195 + (b >> 3)) : b;
    int r0 = grp * GR;
    int ch = lane * 4;
    const float4* H4 = (const float4*)h1;

    if (f32) {
        unsigned short* pH = (unsigned short*)lds;
        unsigned short* pM = pH + GR * APAD;
        unsigned short* pL = pM + GR * APAD;
        float* redR = (float*)(lds + 3 * GR * APAD * 2);
        float* redO = redR + 128;

        // ---- batched metadata preload for the 8 rows ----
        int begs[8], ends[8];
#pragma unroll
        for (int rr = 0; rr < 8; ++rr) {
            int row = min(r0 + rg * 8 + rr, NN - 1);
            begs[rr] = offsets[row];
            ends[rr] = offsets[row + 1];
        }
        int   sl8[8];
        float dv8[8];
#pragma unroll
        for (int rr = 0; rr < 8; ++rr) {
            int cnt0 = min(64, ends[rr] - begs[rr]);
            int p = begs[rr] + ((lane < cnt0) ? lane : 0);
            p = min(p, EE - 1);
            sl8[rr] = eidx[p];
        }
#pragma unroll
        for (int rr = 0; rr < 8; ++rr) dv8[rr] = dinv[sl8[rr]];

        // ---- stage: gather 8 agg2 rows per wave, split to 3 bf16 planes ----
        for (int rr = 0; rr < 8; ++rr) {
            int row = r0 + rg * 8 + rr;
            float4 acc = make_float4(0.f, 0.f, 0.f, 0.f);
            if (row < NN) {
                int beg = begs[rr], end = ends[rr];
                int sl = sl8[rr];
                float dvl = dv8[rr];
                for (int base = beg; base < end; base += 64) {
                    int cnt = min(64, end - base);
                    if (base != beg) {          // chunks >=2: rare (deg>64)
                        int p = base + ((lane < cnt) ? lane : 0);
                        sl = eidx[p];
                        dvl = dinv[sl];
                    }
                    int q = 0;
                    for (; q + 4 <= cnt; q += 4) {
                        int s0 = rli(sl, q), s1 = rli(sl, q + 1);
                        int s2 = rli(sl, q + 2), s3 = rli(sl, q + 3);
                        float d0 = rlf(dvl, q), d1 = rlf(dvl, q + 1);
                        float d2 = rlf(dvl, q + 2), d3 = rlf(dvl, q + 3);
                        float4 v0 = H4[(s0 * HH + ch) >> 2];
                        float4 v1 = H4[(s1 * HH + ch) >> 2];
                        float4 v2 = H4[(s2 * HH + ch) >> 2];
                        float4 v3 = H4[(s3 * HH + ch) >> 2];
                        acc.x += d0 * v0.x; acc.y += d0 * v0.y; acc.z += d0 * v0.z; acc.w += d0 * v0.w;
                        acc.x += d1 * v1.x; acc.y += d1 * v1.y; acc.z += d1 * v1.z; acc.w += d1 * v1.w;
                        acc.x += d2 * v2.x; acc.y += d2 * v2.y; acc.z += d2 * v2.z; acc.w += d2 * v2.w;
                        acc.x += d3 * v3.x; acc.y += d3 * v3.y; acc.z += d3 * v3.z; acc.w += d3 * v3.w;
                    }
                    for (; q < cnt; ++q) {
                        int s    = rli(sl, q);
                        float dv = rlf(dvl, q);
                        float4 v = H4[(s * HH + ch) >> 2];
                        acc.x += dv * v.x; acc.y += dv * v.y;
                        acc.z += dv * v.z; acc.w += dv * v.w;
                    }
                }
                float di = dinv[row];
                float d2 = di * di;
                float4 v = H4[(row * HH + ch) >> 2];
                acc.x = di * acc.x + d2 * v.x;
                acc.y = di * acc.y + d2 * v.y;
                acc.z = di * acc.z + d2 * v.z;
                acc.w = di * acc.w + d2 * v.w;
            }
            ushort4 hv, mv, lv;
            split3(acc.x, hv.x, mv.x, lv.x);
            split3(acc.y, hv.y, mv.y, lv.y);
            split3(acc.z, hv.z, mv.z, lv.z);
            split3(acc.w, hv.w, mv.w, lv.w);
            int base = (rg * 8 + rr) * APAD + ch;
            *(ushort4*)(pH + base) = hv;
            *(ushort4*)(pM + base) = mv;
            *(ushort4*)(pL + base) = lv;
        }
        __syncthreads();   // cross-wave: A-frag reads span all 32 rows

        // ---- compute: 8 k-steps x (2 mt x 4 nt) tiles x 6 split products ----
        int quad = lane >> 4, l15 = lane & 15;
        int nt0 = rg * 4;
        f32x4 acc[2][4];
#pragma unroll
        for (int mt = 0; mt < 2; ++mt)
#pragma unroll
            for (int nt = 0; nt < 4; ++nt) acc[mt][nt] = (f32x4)0.f;

#pragma unroll
        for (int ks = 0; ks < 8; ++ks) {
            short8 aH[2], aM[2], aL[2];
#pragma unroll
            for (int mt = 0; mt < 2; ++mt) {
                int boff = (mt * 16 + l15) * APAD + ks * 32 + quad * 8;
                aH[mt] = *(const short8*)(pH + boff);
                aM[mt] = *(const short8*)(pM + boff);
                aL[mt] = *(const short8*)(pL + boff);
            }
            short8 bH[4], bM[4], bL[4];
#pragma unroll
            for (int nt = 0; nt < 4; ++nt) {
                int e = ((nt0 + nt) * 8 + ks) * 64 + lane;
                bH[nt] = Bf[e];
                bM[nt] = Bf[e + 8192];
                bL[nt] = Bf[e + 16384];
            }
#pragma unroll
            for (int mt = 0; mt < 2; ++mt)
#pragma unroll
                for (int nt = 0; nt < 4; ++nt)
                    acc[mt][nt] = __builtin_amdgcn_mfma_f32_16x16x32_bf16(aH[mt], bH[nt], acc[mt][nt], 0, 0, 0);
#pragma unroll
            for (int mt = 0; mt < 2; ++mt)
#pragma unroll
                for (int nt = 0; nt < 4; ++nt)
                    acc[mt][nt] = __builtin_amdgcn_mfma_f32_16x16x32_bf16(aM[mt], bH[nt], acc[mt][nt], 0, 0, 0);
#pragma unroll
            for (int mt = 0; mt < 2; ++mt)
#pragma unroll
                for (int nt = 0; nt < 4; ++nt)
                    acc[mt][nt] = __builtin_amdgcn_mfma_f32_16x16x32_bf16(aH[mt], bM[nt], acc[mt][nt], 0, 0, 0);
#pragma unroll
            for (int mt = 0; mt < 2; ++mt)
#pragma unroll
                for (int nt = 0; nt < 4; ++nt)
                    acc[mt][nt] = __builtin_amdgcn_mfma_f32_16x16x32_bf16(aL[mt], bH[nt], acc[mt][nt], 0, 0, 0);
#pragma unroll
            for (int mt = 0; mt < 2; ++mt)
#pragma unroll
                for (int nt = 0; nt < 4; ++nt)
                    acc[mt][nt] = __builtin_amdgcn_mfma_f32_16x16x32_bf16(aH[mt], bL[nt], acc[mt][nt], 0, 0, 0);
#pragma unroll
            for (int mt = 0; mt < 2; ++mt)
#pragma unroll
                for (int nt = 0; nt < 4; ++nt)
                    acc[mt][nt] = __builtin_amdgcn_mfma_f32_16x16x32_bf16(aM[mt], bM[nt], acc[mt][nt], 0, 0, 0);
        }

        // ---- epilogue: relu + store + fused scorer dots ----
        const float* b2f = (const float*)b2;
        const float* wrf = (const float*)Wrel;
        const float* wof = (const float*)Wroot;
        float b2v[4], wrv[4], wov[4];
#pragma unroll
        for (int nt = 0; nt < 4; ++nt) {
            int col = (nt0 + nt) * 16 + l15;
            b2v[nt] = b2f[col]; wrv[nt] = wrf[col]; wov[nt] = wof[col];
        }
#pragma unroll
        for (int mt = 0; mt < 2; ++mt) {
#pragma unroll
            for (int r = 0; r < 4; ++r) {
                int row = r0 + mt * 16 + quad * 4 + r;
                float sr = 0.f, so = 0.f;
#pragma unroll
                for (int nt = 0; nt < 4; ++nt) {
                    float y = fmaxf(acc[mt][nt][r] + b2v[nt], 0.f);
                    if (row < NN) Y[row * HH + (nt0 + nt) * 16 + l15] = y;
                    sr += y * wrv[nt];
                    so += y * wov[nt];
                }
#pragma unroll
                for (int off = 1; off < 16; off <<= 1) {
                    sr += __shfl_xor(sr, off, 64);
                    so += __shfl_xor(so, off, 64);
                }
                if (l15 == 0) {
                    redR[(mt * 16 + quad * 4 + r) * 4 + rg] = sr;
                    redO[(mt * 16 + quad * 4 + r) * 4 + rg] = so;
                }
            }
        }
        __syncthreads();
        if (t < GR) {
            int row = r0 + t;
            if (row < NN) {
                trel[row]  = redR[t * 4] + redR[t * 4 + 1] + redR[t * 4 + 2] + redR[t * 4 + 3];
                troot[row] = redO[t * 4] + redO[t * 4 + 1] + redO[t * 4 + 2] + redO[t * 4 + 3];
            }
        }
        return;
    }

    // ---------------- bf16-input fallback: r12 pk-fma path ----------------
    {
        float (*As)[HH] = (float (*)[HH])lds;
        int c4 = lane;
        for (int rr = 0; rr < 8; ++rr) {
            int row = r0 + rg * 8 + rr;
            float4 acc = make_float4(0.f, 0.f, 0.f, 0.f);
            if (row < NN) {
                int beg = offsets[row], end = offsets[row + 1];
                for (int base = beg; base < end; base += 64) {
                    int cnt = min(64, end - base);
                    int p  = base + ((lane < cnt) ? lane : 0);
                    int sl = eidx[p];
                    float dvl = dinv[sl];
                    for (int q = 0; q < cnt; ++q) {
                        int s    = rli(sl, q);
                        float dv = rlf(dvl, q);
                        float4 v = H4[(s * HH + ch) >> 2];
                        acc.x += dv * v.x; acc.y += dv * v.y;
                        acc.z += dv * v.z; acc.w += dv * v.w;
                    }
                }
                float di = dinv[row];
                float d2 = di * di;
                float4 v = H4[(row * HH + ch) >> 2];
                acc.x = di * acc.x + d2 * v.x;
                acc.y = di * acc.y + d2 * v.y;
                acc.z = di * acc.z + d2 * v.z;
                acc.w = di * acc.w + d2 * v.w;
            }
            *(float4*)&As[rg * 8 + rr][ch] = acc;
        }
        // no barrier: tile slice is wave-private

        v2f accL[8], accH[8];
#pragma unroll
        for (int rr = 0; rr < 8; ++rr) { accL[rr] = (v2f)0.f; accH[rr] = (v2f)0.f; }
        const unsigned short* W = (const unsigned short*)W2;
        ushort4 u0 = *(const ushort4*)&W[0 * HH + c4 * 4];
        ushort4 u1 = *(const ushort4*)&W[1 * HH + c4 * 4];
        ushort4 u2 = *(const ushort4*)&W[2 * HH + c4 * 4];
        ushort4 u3 = *(const ushort4*)&W[3 * HH + c4 * 4];
        for (int k = 0; k < 256; k += 4) {
            ushort4 m0, m1, m2, m3;
            int kn = (k + 4) & 255;
            m0 = *(const ushort4*)&W[(kn + 0) * HH + c4 * 4];
            m1 = *(const ushort4*)&W[(kn + 1) * HH + c4 * 4];
            m2 = *(const ushort4*)&W[(kn + 2) * HH + c4 * 4];
            m3 = *(const ushort4*)&W[(kn + 3) * HH + c4 * 4];
            v2f w0L = {bfbits(u0.x), bfbits(u0.y)}, w0H = {bfbits(u0.z), bfbits(u0.w)};
            v2f w1L = {bfbits(u1.x), bfbits(u1.y)}, w1H = {bfbits(u1.z), bfbits(u1.w)};
            v2f w2L = {bfbits(u2.x), bfbits(u2.y)}, w2H = {bfbits(u2.z), bfbits(u2.w)};
            v2f w3L = {bfbits(u3.x), bfbits(u3.y)}, w3H = {bfbits(u3.z), bfbits(u3.w)};
#pragma unroll
            for (int rr = 0; rr < 8; ++rr) {
                float4 a = *(const float4*)&As[rg * 8 + rr][k];
                v2f ax = a.x, ay = a.y, az = a.z, aw = a.w;
                accL[rr] += ax * w0L; accH[rr] += ax * w0H;
                accL[rr] += ay * w1L; accH[rr] += ay * w1H;
                accL[rr] += az * w2L; accH[rr] += az * w2H;
                accL[rr] += aw * w3L; accH[rr] += aw * w3H;
            }
            u0 = m0; u1 = m1; u2 = m2; u3 = m3;
        }
        float4 bb = ldf4(b2, c4 * 4, f32);
        float4 wr = ldf4(Wrel, c4 * 4, f32);
        float4 wo = ldf4(Wroot, c4 * 4, f32);
#pragma unroll
        for (int rr = 0; rr < 8; ++rr) {
            int row = r0 + rg * 8 + rr;
            float4 y;
            y.x = fmaxf(accL[rr].x + bb.x, 0.f);
            y.y = fmaxf(accL[rr].y + bb.y, 0.f);
            y.z = fmaxf(accH[rr].x + bb.z, 0.f);
            y.w = fmaxf(accH[rr].y + bb.w, 0.f);
            if (row < NN)
                *(float4*)&Y[row * HH + c4 * 4] = y;
            float sr = y.x * wr.x + y.y * wr.y + y.z * wr.z + y.w * wr.w;
            float so = y.x * wo.x + y.y * wo.y + y.z * wo.z + y.w * wo.w;
#pragma unroll
            for (int off = 32; off > 0; off >>= 1) {
                sr += __shfl_xor(sr, off, 64);
                so += __shfl_xor(so, off, 64);
            }
            if (c4 == 0 && row < NN) { trel[row] = sr; troot[row] = so; }
        }
    }
}

// ---------------- score -> per-graph top-k (selection only) ----------------
// One block per graph, 1024 threads. Desc score, asc index = jax tie-break.
// Writes snode/sw to global; pooling moved to k_pool (full-device grid).

__global__ __launch_bounds__(1024) void k_topk(
        const int* __restrict__ offsets, const int* __restrict__ eidx,
        const float* __restrict__ trel, const float* __restrict__ troot,
        const void* __restrict__ brel, const int* __restrict__ flag,
        int* __restrict__ snode, float* __restrict__ sw) {
    __shared__ float s[1024];
    __shared__ int   id[1024];
    bool f32 = (*flag != 0);
    int b = blockIdx.x, t = threadIdx.x;
    float br = ldf(brel, 0, f32);
    if (t < NPGc) {
        int node = b * NPGc + t;
        float sc = br + troot[node];
        int beg = offsets[node], end = offsets[node + 1];
        for (int p = beg; p < end; ++p) sc += trel[eidx[p]];
        s[t] = sc; id[t] = t;
    } else { s[t] = -FLT_MAX; id[t] = 0x7FFFFFFF; }
    for (int k = 2; k <= 1024; k <<= 1) {
        for (int j = k >> 1; j > 0; j >>= 1) {
            __syncthreads();
            int l = t ^ j;
            if (l > t) {
                float si = s[t], sl = s[l];
                int   ii = id[t], il = id[l];
                bool iFirst = (si > sl) || (si == sl && ii < il);
                bool doSwap = ((t & k) == 0) ? (!iFirst) : iFirst;
                if (doSwap) { s[t] = sl; s[l] = si; id[t] = il; id[l] = ii; }
            }
        }
    }
    __syncthreads();
    if (t < KK) {
        snode[b * KK + t] = b * NPGc + id[t];
        sw[b * KK + t]    = tanhf(s[t]);
    }
}

// ---------------- pool: partial max over 63-row slices, 8 blocks/graph ----------

__global__ __launch_bounds__(256) void k_pool(
        const int* __restrict__ snode, const float* __restrict__ sw,
        const float* __restrict__ h2, float* __restrict__ part) {
    __shared__ int   sn[64];
    __shared__ float sv[64];
    int b = blockIdx.x >> 3;
    int j = blockIdx.x & 7;
    int t = threadIdx.x;
    int q0 = j * 63;
    int cnt = min(63, KK - q0);
    if (t < cnt) {
        sn[t] = snode[b * KK + q0 + t];
        sv[t] = sw[b * KK + q0 + t];
    }
    __syncthreads();
    float m = -FLT_MAX;
    for (int q = 0; q < cnt; ++q)
        m = fmaxf(m, h2[sn[q] * HH + t] * sv[q]);
    part[blockIdx.x * 256 + t] = m;
}

__global__ __launch_bounds__(256) void k_out(
        const float* __restrict__ part, const int* __restrict__ flag,
        void* __restrict__ out) {
    int b = blockIdx.x, t = threadIdx.x;
    float r = part[(b * 8 + 0) * 256 + t];
#pragma unroll
    for (int j = 1; j < 8; ++j)
        r = fmaxf(r, part[(b * 8 + j) * 256 + t]);
    if (*flag) ((float*)out)[b * HH + t] = r;
    else       ((bf16*)out)[b * HH + t] = __float2bfloat16(r);
}

// ---------------- launch ----------------

extern "C" void kernel_launch(void* const* d_in, const int* in_sizes, int n_in,
                              void* d_out, int out_size, void* d_ws, size_t ws_size,
                              hipStream_t stream) {
    const int*  x    = (const int*)d_in[0];
    const int*  esrc = (const int*)d_in[1];
    const int*  edst = esrc + EE;
    const void* W1   = d_in[3];
    const void* b1   = d_in[4];
    const void* W2   = d_in[5];
    const void* b2   = d_in[6];
    const void* Wrel = d_in[7];
    const void* brel = d_in[8];
    const void* Wroot= d_in[9];

    char* w = (char*)d_ws;
    size_t off = 0;
    auto carve = [&](size_t bytes) -> void* {
        void* p = w + off;
        off = (off + bytes + 255) & ~(size_t)255;
        return p;
    };
    int*    flag    = (int*)   carve(256);
    int*    deg     = (int*)   carve((size_t)NN * 4);
    int*    partial = (int*)   carve((size_t)NN * 4);
    int*    bsums   = (int*)   carve(256 * 4);
    int*    offsets = (int*)   carve((size_t)(NN + 1) * 4);
    int*    eidx    = (int*)   carve((size_t)EE * 4);
    int*    pose    = (int*)   carve((size_t)EE * 4);
    float*  dinv    = (float*) carve((size_t)NN * 4);
    float*  trel    = (float*) carve((size_t)NN * 4);
    float*  troot   = (float*) carve((size_t)NN * 4);
    int*    snode   = (int*)   carve((size_t)BB * KK * 4);
    float*  swb     = (float*) carve((size_t)BB * KK * 4);
    float*  part    = (float*) carve((size_t)BB * 8 * 256 * 4);
    short8* Bf      = (short8*)carve((size_t)3 * 8192 * 16);  // W2 bf16x3 B-frags
    float*  bufA    = (float*) carve((size_t)NN * HH * 4);    // h1
    float*  bufB    = (float*) carve((size_t)NN * HH * 4);    // h2
    (void)ws_size; (void)in_sizes; (void)n_in; (void)out_size;

    const int NB   = (NN + 255) / 256;     // 196
    const int EBLK = (EE + 255) / 256;     // 1172
    const int NGB  = (NN + 3) / 4;         // 12500

    hipMemsetAsync(deg, 0, (size_t)NN * 4, stream);
    k_count     <<<EBLK + 1, 256, 0, stream>>>(edst, deg, pose,
                                               (const unsigned int*)W1, flag);
    k_prep      <<<32, 256, 0, stream>>>(W2, flag, Bf);
    k_scan_block<<<NB, 256, 0, stream>>>(deg, partial, bsums);
    k_finalize  <<<NB, 256, 0, stream>>>(deg, partial, bsums, offsets, dinv);
    k_fill      <<<EBLK, 256, 0, stream>>>(esrc, edst, offsets, pose, eidx);

    k_layer1    <<<NGB, 256, 0, stream>>>(x, offsets, eidx, dinv, W1, b1, flag, bufA);
    k_gemm2     <<<(NN + GR - 1) / GR, 256, 0, stream>>>(offsets, eidx, dinv, bufA,
                                                         W2, b2, Wrel, Wroot, flag,
                                                         Bf, bufB, trel, troot);
    k_topk      <<<BB, 1024, 0, stream>>>(offsets, eidx, trel, troot, brel, flag,
                                          snode, swb);
    k_pool      <<<BB * 8, 256, 0, stream>>>(snode, swb, bufB, part);
    k_out       <<<BB, 256, 0, stream>>>(part, flag, d_out);
}